// Round 12
// baseline (3924.779 us; speedup 1.0000x reference)
//
#include <hip/hip_runtime.h>
#include <stdint.h>

typedef unsigned short u16;
typedef unsigned int u32;
typedef __attribute__((ext_vector_type(4))) float f32x4;
typedef __attribute__((ext_vector_type(8))) short short8;

#define MFMA16(a, b, c) __builtin_amdgcn_mfma_f32_16x16x32_bf16(a, b, c, 0, 0, 0)

// ---------- sizes ----------
#define B_SZ   4096
#define H_SZ   1024
#define T_SZ   32
#define NROLL  130
#define EXTK   192   // rhy(3)+cond(12)+z1(128)=143, padded to 3x64
#define NCPAD  144   // 130 padded to 9x16

__device__ __forceinline__ u16 f2b(float f) {
  u32 u = __float_as_uint(f);
  u += 0x7FFFu + ((u >> 16) & 1u);
  return (u16)(u >> 16);
}
__device__ __forceinline__ float sigm(float x) { return 1.f / (1.f + __expf(-x)); }

// async global->LDS (16B). LDS dest = wave-uniform base + lane*16 (linear).
__device__ __forceinline__ void gld16(const void* g, const void* lds) {
  __builtin_amdgcn_global_load_lds(
      (const __attribute__((address_space(1))) u32*)(uintptr_t)g,
      (__attribute__((address_space(3))) u32*)(u32)(uintptr_t)lds, 16, 0, 0);
}

// ---------------- setup kernels ----------------
__global__ void cvt_kernel(const float* __restrict__ s, u16* __restrict__ d, int n) {
  int i = blockIdx.x * 256 + threadIdx.x;
  if (i < n) d[i] = f2b(s[i]);
}

__global__ void build_wout_kernel(const float* __restrict__ w, u16* __restrict__ d) {
  int i = blockIdx.x * 256 + threadIdx.x;           // 144*1024
  int r = i >> 10, c = i & 1023;
  d[i] = f2b(r < NROLL ? w[r * H_SZ + c] : 0.f);
}

__global__ void build_wext_kernel(const float* __restrict__ w, u16* __restrict__ d) {
  int i = blockIdx.x * 256 + threadIdx.x;           // 3072*192
  int j = i / EXTK, k = i % EXTK;
  float v = 0.f;
  if (k < 3)        v = w[j * 273 + 130 + k];
  else if (k < 15)  v = w[j * 273 + 261 + (k - 3)];
  else if (k < 143) v = w[j * 273 + 133 + (k - 15)];
  d[i] = f2b(v);
}

__global__ void build_wih1T_kernel(const float* __restrict__ w, float* __restrict__ d) {
  int i = blockIdx.x * 256 + threadIdx.x;           // 130*3072
  if (i >= NROLL * 3072) return;
  int c = i / 3072, j = i % 3072;
  d[i] = w[j * 273 + c];
}

// Aext[t][b][k]: [rhy(3), cond(12), z1(128), 0...]
__global__ void build_aext_kernel(const float* __restrict__ rhy, const float* __restrict__ cond,
                                  const float* __restrict__ z1, u16* __restrict__ d) {
  long long i = (long long)blockIdx.x * 256 + threadIdx.x;  // 32*4096*192
  int t = (int)(i / (B_SZ * EXTK));
  int r = (int)(i % (B_SZ * EXTK));
  int b = r / EXTK, k = r % EXTK;
  float v = 0.f;
  if (k < 3)        v = rhy[b * (T_SZ * 3) + t * 3 + k];
  else if (k < 15)  v = cond[b * (T_SZ * 12) + t * 12 + (k - 3)];
  else if (k < 143) v = z1[b * 128 + (k - 15)];
  d[i] = f2b(v);
}

__global__ void init_amax_kernel(int* __restrict__ a) {
  a[blockIdx.x * 256 + threadIdx.x] = NROLL - 1;  // one-hot at last col
}

// h1_0 = tanh(z1 @ w_init^T + b_init), MFMA.
__global__ __launch_bounds__(256, 2)
void init_h1_mfma_kernel(const u16* __restrict__ Az,  // z1 bf16 [4096][128]
                         const u16* __restrict__ Wz,  // w_init bf16 [1024][128]
                         const float* __restrict__ b_init,
                         float* __restrict__ h1f, u16* __restrict__ h1b) {
  __shared__ u16 As[128 * 64];
  __shared__ u16 Ws[64 * 64];
  const int tid = threadIdx.x;
  const int lane = tid & 63, wv = tid >> 6;
  const int wm = wv >> 1, wn = wv & 1;
  const int lr = lane & 15, lk = lane >> 4;
  const int Mbase = blockIdx.x * 128, Nbase = blockIdx.y * 64;

  f32x4 zero = {0.f, 0.f, 0.f, 0.f};
  f32x4 acc[4][2];
#pragma unroll
  for (int m = 0; m < 4; ++m)
#pragma unroll
    for (int n = 0; n < 2; ++n) acc[m][n] = zero;

  for (int it = 0; it < 2; ++it) {
#pragma unroll
    for (int i = 0; i < 4; ++i) {
      int seg = i * 256 + tid, row = seg >> 3, c8 = seg & 7;
      gld16(Az + (size_t)(Mbase + row) * 128 + it * 64 + c8 * 8, As + ((i * 256 + (wv << 6)) << 3));
    }
#pragma unroll
    for (int i = 0; i < 2; ++i) {
      int seg = i * 256 + tid, row = seg >> 3, c8 = seg & 7;
      gld16(Wz + (size_t)(Nbase + row) * 128 + it * 64 + c8 * 8, Ws + ((i * 256 + (wv << 6)) << 3));
    }
    __syncthreads();
#pragma unroll
    for (int kk = 0; kk < 2; ++kk) {
      short8 af[4];
#pragma unroll
      for (int m = 0; m < 4; ++m)
        af[m] = *(const short8*)(As + (((wm << 6) + (m << 4) + lr) << 6) + kk * 32 + (lk << 3));
      short8 bw[2];
#pragma unroll
      for (int n = 0; n < 2; ++n)
        bw[n] = *(const short8*)(Ws + ((((wn << 5) + (n << 4) + lr)) << 6) + kk * 32 + (lk << 3));
#pragma unroll
      for (int m = 0; m < 4; ++m)
#pragma unroll
        for (int n = 0; n < 2; ++n)
          acc[m][n] = MFMA16(af[m], bw[n], acc[m][n]);
    }
    __syncthreads();
  }

  int hcol[2];
  hcol[0] = Nbase + (wn << 5) + lr;
  hcol[1] = hcol[0] + 16;
#pragma unroll
  for (int m = 0; m < 4; ++m) {
#pragma unroll
    for (int q = 0; q < 4; ++q) {
      int b = Mbase + (wm << 6) + (m << 4) + (lk << 2) + q;
      size_t ho = (size_t)b << 10;
#pragma unroll
      for (int n = 0; n < 2; ++n) {
        int h = hcol[n];
        float v = tanhf(acc[m][n][q] + b_init[h]);
        h1f[ho + h] = v;
        h1b[ho + h] = f2b(v);
      }
    }
  }
}

// ---- GRU cell 1: lockstep BK=128 main + BK=64 ext, XOR chunk swizzle, T5 setprio ----
__global__ __launch_bounds__(256, 2)
void gru1_kernel(const u16* __restrict__ Ah,   // h1 bf16 [B][1024]
                 const u16* __restrict__ Whh,  // w_hh1 bf16 [3072][1024]
                 const u16* __restrict__ Ae,   // Aext_t bf16 [B][192]
                 const u16* __restrict__ Wex,  // Wext bf16 [3072][192]
                 const float* __restrict__ gT, // w_ih1T [130][3072]
                 const float* __restrict__ bih, const float* __restrict__ bhh,
                 const int* __restrict__ amax,
                 float* __restrict__ h1f, u16* __restrict__ h1o) {
  __shared__ u16 smem[40960];   // 80 KB: As 128x128 (32KB) + Ws 192x128 (48KB)
  u16* As = smem;               // main: [128][128]; ext: [128][64]
  u16* Wsm = smem + 16384;      // main: [192][128]; ext: [192][64]
  const int tid = threadIdx.x;
  const int lane = tid & 63, wv = tid >> 6;
  const int wm = wv >> 1, wn = wv & 1;
  const int lr = lane & 15, lk = lane >> 4;
  const int Mbase = blockIdx.x * 128, Nbase = blockIdx.y * 64;

  f32x4 zero = {0.f, 0.f, 0.f, 0.f};
  f32x4 acc_r[4][2], acc_z[4][2], acc_hn[4][2], acc_in[4][2];
#pragma unroll
  for (int m = 0; m < 4; ++m)
#pragma unroll
    for (int n = 0; n < 2; ++n) { acc_r[m][n] = zero; acc_z[m][n] = zero; acc_hn[m][n] = zero; acc_in[m][n] = zero; }

  // ---- main phase: K=1024 in 8 iters of BK=128 ----
#pragma unroll 1
  for (int it = 0; it < 8; ++it) {
#pragma unroll
    for (int i = 0; i < 8; ++i) {     // A: 128 rows x 128 cols
      int seg = i * 256 + tid, row = seg >> 4, c16 = (seg & 15) ^ (row & 7);
      gld16(Ah + (size_t)(Mbase + row) * 1024 + it * 128 + c16 * 8, As + ((i * 256 + (wv << 6)) << 3));
    }
#pragma unroll
    for (int i = 0; i < 12; ++i) {    // W: 192 rows x 128 cols
      int seg = i * 256 + tid, gr = seg >> 4, c16 = (seg & 15) ^ (gr & 7);
      int gg = gr >> 6, r = gr & 63;
      gld16(Whh + ((size_t)(gg << 10) + Nbase + r) * 1024 + it * 128 + c16 * 8,
            Wsm + ((i * 256 + (wv << 6)) << 3));
    }
    __syncthreads();
    __builtin_amdgcn_s_setprio(1);
#pragma unroll
    for (int kk = 0; kk < 4; ++kk) {
      int gc = (kk << 2) + lk;        // global chunk16 wanted
      short8 af[4];
#pragma unroll
      for (int m = 0; m < 4; ++m) {
        int row = (wm << 6) + (m << 4) + lr;
        af[m] = *(const short8*)(As + (row << 7) + ((gc ^ (row & 7)) << 3));
      }
      short8 bw[3][2];
#pragma unroll
      for (int g = 0; g < 3; ++g)
#pragma unroll
        for (int n = 0; n < 2; ++n) {
          int row = (g << 6) + (wn << 5) + (n << 4) + lr;
          bw[g][n] = *(const short8*)(Wsm + (row << 7) + ((gc ^ (row & 7)) << 3));
        }
#pragma unroll
      for (int m = 0; m < 4; ++m)
#pragma unroll
        for (int n = 0; n < 2; ++n) {
          acc_r[m][n] = MFMA16(af[m], bw[0][n], acc_r[m][n]);
          acc_z[m][n] = MFMA16(af[m], bw[1][n], acc_z[m][n]);
          acc_hn[m][n] = MFMA16(af[m], bw[2][n], acc_hn[m][n]);
        }
    }
    __builtin_amdgcn_s_setprio(0);
    __syncthreads();
  }

  // ---- ext phase: K=192 in 3 iters of BK=64 ----
#pragma unroll 1
  for (int e = 0; e < 3; ++e) {
#pragma unroll
    for (int i = 0; i < 4; ++i) {     // A: 128 rows x 64 cols
      int seg = i * 256 + tid, row = seg >> 3, c8 = (seg & 7) ^ (row & 7);
      gld16(Ae + (size_t)(Mbase + row) * EXTK + e * 64 + c8 * 8, As + ((i * 256 + (wv << 6)) << 3));
    }
#pragma unroll
    for (int i = 0; i < 6; ++i) {     // W: 192 rows x 64 cols
      int seg = i * 256 + tid, gr = seg >> 3, c8 = (seg & 7) ^ (gr & 7);
      int gg = gr >> 6, r = gr & 63;
      gld16(Wex + ((size_t)(gg << 10) + Nbase + r) * EXTK + e * 64 + c8 * 8,
            Wsm + ((i * 256 + (wv << 6)) << 3));
    }
    __syncthreads();
    __builtin_amdgcn_s_setprio(1);
#pragma unroll
    for (int kk = 0; kk < 2; ++kk) {
      int gc = (kk << 2) + lk;        // global chunk8 wanted
      short8 af[4];
#pragma unroll
      for (int m = 0; m < 4; ++m) {
        int row = (wm << 6) + (m << 4) + lr;
        af[m] = *(const short8*)(As + (row << 6) + ((gc ^ (row & 7)) << 3));
      }
      short8 bw[3][2];
#pragma unroll
      for (int g = 0; g < 3; ++g)
#pragma unroll
        for (int n = 0; n < 2; ++n) {
          int row = (g << 6) + (wn << 5) + (n << 4) + lr;
          bw[g][n] = *(const short8*)(Wsm + (row << 6) + ((gc ^ (row & 7)) << 3));
        }
#pragma unroll
      for (int m = 0; m < 4; ++m)
#pragma unroll
        for (int n = 0; n < 2; ++n) {
          acc_r[m][n] = MFMA16(af[m], bw[0][n], acc_r[m][n]);
          acc_z[m][n] = MFMA16(af[m], bw[1][n], acc_z[m][n]);
          acc_in[m][n] = MFMA16(af[m], bw[2][n], acc_in[m][n]);
        }
    }
    __builtin_amdgcn_s_setprio(0);
    __syncthreads();
  }

  // epilogue (scatter form; 16-lane groups fill 64B lines)
  int hcol[2];
  hcol[0] = Nbase + (wn << 5) + lr;
  hcol[1] = hcol[0] + 16;
  float bi0[2], bi1[2], bi2[2], bh0[2], bh1[2], bh2[2];
#pragma unroll
  for (int n = 0; n < 2; ++n) {
    int h = hcol[n];
    bi0[n] = bih[h]; bi1[n] = bih[1024 + h]; bi2[n] = bih[2048 + h];
    bh0[n] = bhh[h]; bh1[n] = bhh[1024 + h]; bh2[n] = bhh[2048 + h];
  }
#pragma unroll
  for (int m = 0; m < 4; ++m) {
#pragma unroll
    for (int q = 0; q < 4; ++q) {
      int b = Mbase + (wm << 6) + (m << 4) + (lk << 2) + q;
      const float* gRow = gT + (size_t)amax[b] * 3072;
      size_t ho = (size_t)b << 10;
#pragma unroll
      for (int n = 0; n < 2; ++n) {
        int h = hcol[n];
        float rp = acc_r[m][n][q] + bi0[n] + bh0[n] + gRow[h];
        float zp = acc_z[m][n][q] + bi1[n] + bh1[n] + gRow[1024 + h];
        float inp = acc_in[m][n][q] + bi2[n] + gRow[2048 + h];
        float hnp = acc_hn[m][n][q] + bh2[n];
        float r = sigm(rp), z = sigm(zp);
        float nn = tanhf(inp + r * hnp);
        float hv = (1.f - z) * nn + z * h1f[ho + h];
        h1f[ho + h] = hv;
        h1o[ho + h] = f2b(hv);
      }
    }
  }
}

// ---- GRU cell 2: 64x64 tile, split-phase (A1*Wi then A2*Wh), 4 blocks/CU ----
__global__ __launch_bounds__(256, 4)
void gru2_kernel(const u16* __restrict__ A1,  // h1_new bf16
                 const u16* __restrict__ A2,  // h2_prev bf16 (h1_new at t=0)
                 const u16* __restrict__ Wi,  // w_ih2 bf16
                 const u16* __restrict__ Wh,  // w_hh2 bf16
                 const float* __restrict__ bih, const float* __restrict__ bhh,
                 const float* __restrict__ hpf,  // h2_prev f32 (h1f at t=0)
                 float* __restrict__ h2f, u16* __restrict__ h2o) {
  __shared__ u16 As[64 * 64];    // 8 KB
  __shared__ u16 Ws[192 * 64];   // 24 KB  -> 32 KB total, 4 blocks/CU
  const int tid = threadIdx.x;
  const int lane = tid & 63, wv = tid >> 6;
  const int wm = wv >> 1, wn = wv & 1;   // 2x2 waves over 64x64
  const int lr = lane & 15, lk = lane >> 4;
  const int Mbase = blockIdx.x * 64, Nbase = blockIdx.y * 64;

  f32x4 zero = {0.f, 0.f, 0.f, 0.f};
  f32x4 acc_r[2][2], acc_z[2][2], acc_in[2][2], acc_hn[2][2];
#pragma unroll
  for (int m = 0; m < 2; ++m)
#pragma unroll
    for (int n = 0; n < 2; ++n) { acc_r[m][n] = zero; acc_z[m][n] = zero; acc_in[m][n] = zero; acc_hn[m][n] = zero; }

#pragma unroll
  for (int p = 0; p < 2; ++p) {
    const u16* Ap = p ? A2 : A1;
    const u16* Wp = p ? Wh : Wi;
#pragma unroll 1
    for (int it = 0; it < 16; ++it) {
#pragma unroll
      for (int i = 0; i < 2; ++i) {   // A: 64 rows x 64 cols
        int seg = i * 256 + tid, row = seg >> 3, c8 = (seg & 7) ^ (row & 7);
        gld16(Ap + (size_t)(Mbase + row) * 1024 + it * 64 + c8 * 8, As + ((i * 256 + (wv << 6)) << 3));
      }
#pragma unroll
      for (int i = 0; i < 6; ++i) {   // W: 3 gates x 64 rows x 64 cols
        int seg = i * 256 + tid, gr = seg >> 3, c8 = (seg & 7) ^ (gr & 7);
        int g = gr >> 6, r = gr & 63;
        gld16(Wp + ((size_t)((g << 10) + Nbase + r)) * 1024 + it * 64 + c8 * 8,
              Ws + ((i * 256 + (wv << 6)) << 3));
      }
      __syncthreads();
      __builtin_amdgcn_s_setprio(1);
#pragma unroll
      for (int kk = 0; kk < 2; ++kk) {
        int gc = (kk << 2) + lk;
        short8 af[2];
#pragma unroll
        for (int m = 0; m < 2; ++m) {
          int row = (wm << 5) + (m << 4) + lr;
          af[m] = *(const short8*)(As + (row << 6) + ((gc ^ (row & 7)) << 3));
        }
        short8 bw[3][2];
#pragma unroll
        for (int g = 0; g < 3; ++g)
#pragma unroll
          for (int n = 0; n < 2; ++n) {
            int row = (g << 6) + (wn << 5) + (n << 4) + lr;
            bw[g][n] = *(const short8*)(Ws + (row << 6) + ((gc ^ (row & 7)) << 3));
          }
#pragma unroll
        for (int m = 0; m < 2; ++m)
#pragma unroll
          for (int n = 0; n < 2; ++n) {
            acc_r[m][n] = MFMA16(af[m], bw[0][n], acc_r[m][n]);
            acc_z[m][n] = MFMA16(af[m], bw[1][n], acc_z[m][n]);
            if (p == 0) acc_in[m][n] = MFMA16(af[m], bw[2][n], acc_in[m][n]);
            else        acc_hn[m][n] = MFMA16(af[m], bw[2][n], acc_hn[m][n]);
          }
      }
      __builtin_amdgcn_s_setprio(0);
      __syncthreads();
    }
  }

  int hcol[2];
  hcol[0] = Nbase + (wn << 5) + lr;
  hcol[1] = hcol[0] + 16;
  float bi0[2], bi1[2], bi2[2], bh0[2], bh1[2], bh2[2];
#pragma unroll
  for (int n = 0; n < 2; ++n) {
    int h = hcol[n];
    bi0[n] = bih[h]; bi1[n] = bih[1024 + h]; bi2[n] = bih[2048 + h];
    bh0[n] = bhh[h]; bh1[n] = bhh[1024 + h]; bh2[n] = bhh[2048 + h];
  }
#pragma unroll
  for (int m = 0; m < 2; ++m) {
#pragma unroll
    for (int q = 0; q < 4; ++q) {
      int b = Mbase + (wm << 5) + (m << 4) + (lk << 2) + q;
      size_t ho = (size_t)b << 10;
#pragma unroll
      for (int n = 0; n < 2; ++n) {
        int h = hcol[n];
        float r = sigm(acc_r[m][n][q] + bi0[n] + bh0[n]);
        float z = sigm(acc_z[m][n][q] + bi1[n] + bh1[n]);
        float nn = tanhf(acc_in[m][n][q] + bi2[n] + r * (acc_hn[m][n][q] + bh2[n]));
        float hv = (1.f - z) * nn + z * hpf[ho + h];
        h2f[ho + h] = hv;
        h2o[ho + h] = f2b(hv);
      }
    }
  }
}

// ---- logits + log_softmax + argmax: 256 blocks x 128 threads, BK=128 (8 drains) ----
__global__ __launch_bounds__(128)
void out_kernel(const u16* __restrict__ A,   // h2_new bf16
                const u16* __restrict__ W,   // wout bf16 [144][1024]
                const float* __restrict__ b_out,
                float* __restrict__ recon, int* __restrict__ amax_out, int t) {
  __shared__ u16 As[16 * 128];   // 4 KB
  __shared__ u16 Ws[144 * 128];  // 36 KB
  __shared__ float redm[2][16], reds[2][16], logZs[16];
  __shared__ int redi[2][16];
  const int tid = threadIdx.x;
  const int lane = tid & 63, wv = tid >> 6;   // 2 waves
  const int lr = lane & 15, lk = lane >> 4;
  const int bb = blockIdx.x;  // 16 rows each
  const int nf0 = wv ? 5 : 0;                 // first owned frag
  const int nfn = wv ? 4 : 5;                 // owned frag count

  f32x4 zero = {0.f, 0.f, 0.f, 0.f};
  f32x4 acc[5];
#pragma unroll
  for (int j = 0; j < 5; ++j) acc[j] = zero;

  // preload bias per owned frag (invalid col -> -1e30 sentinel)
  float bo[5];
#pragma unroll
  for (int j = 0; j < 5; ++j) {
    int col = ((nf0 + j) << 4) + lr;
    bo[j] = (j < nfn && col < NROLL) ? b_out[col] : -1e30f;
  }

#pragma unroll 1
  for (int it = 0; it < 8; ++it) {
#pragma unroll
    for (int i = 0; i < 2; ++i) {  // A: 16 x 128
      int seg = i * 128 + tid, row = seg >> 4, c16 = seg & 15;
      gld16(A + (size_t)(bb * 16 + row) * 1024 + it * 128 + c16 * 8, As + ((i * 128 + (wv << 6)) << 3));
    }
#pragma unroll
    for (int i = 0; i < 18; ++i) { // W: 144 x 128
      int seg = i * 128 + tid, row = seg >> 4, c16 = seg & 15;
      gld16(W + (size_t)row * 1024 + it * 128 + c16 * 8, Ws + ((i * 128 + (wv << 6)) << 3));
    }
    __syncthreads();
#pragma unroll
    for (int kk = 0; kk < 4; ++kk) {
      short8 af = *(const short8*)(As + (lr << 7) + kk * 32 + (lk << 3));
#pragma unroll 5
      for (int j = 0; j < 5; ++j) {
        if (j < nfn) {
          short8 bw = *(const short8*)(Ws + ((((nf0 + j) << 4) + lr) << 7) + kk * 32 + (lk << 3));
          acc[j] = MFMA16(af, bw, acc[j]);
        }
      }
    }
    __syncthreads();
  }

  // per-wave partial reduce per row, store to LDS
#pragma unroll
  for (int q = 0; q < 4; ++q) {
    int r = (lk << 2) + q;
    float vmax = -1e30f; int vidx = 0;
#pragma unroll 5
    for (int j = 0; j < 5; ++j) {
      if (j < nfn) {
        int col = ((nf0 + j) << 4) + lr;
        float x = acc[j][q] + bo[j];
        if (x > vmax) { vmax = x; vidx = col; }
      }
    }
    for (int d = 1; d < 16; d <<= 1) {
      float om = __shfl_xor(vmax, d);
      int oi = __shfl_xor(vidx, d);
      if (om > vmax || (om == vmax && oi < vidx)) { vmax = om; vidx = oi; }
    }
    float s = 0.f;
#pragma unroll 5
    for (int j = 0; j < 5; ++j) {
      if (j < nfn) s += __expf(acc[j][q] + bo[j] - vmax);
    }
    for (int d = 1; d < 16; d <<= 1) s += __shfl_xor(s, d);
    if (lr == 0) { redm[wv][r] = vmax; reds[wv][r] = s; redi[wv][r] = vidx; }
  }
  __syncthreads();

  // combine the two wave-halves (wave0 = lower cols, wins ties)
  if (tid < 16) {
    float m0 = redm[0][tid], m1 = redm[1][tid];
    float s0 = reds[0][tid], s1 = reds[1][tid];
    float M = fmaxf(m0, m1);
    float S = s0 * __expf(m0 - M) + s1 * __expf(m1 - M);
    logZs[tid] = M + __logf(S);
    amax_out[bb * 16 + tid] = (m1 > m0) ? redi[1][tid] : redi[0][tid];
  }
  __syncthreads();

  // write log-probs
#pragma unroll
  for (int q = 0; q < 4; ++q) {
    int r = (lk << 2) + q;
    int b = bb * 16 + r;
    float lz = logZs[r];
#pragma unroll 5
    for (int j = 0; j < 5; ++j) {
      if (j < nfn) {
        int col = ((nf0 + j) << 4) + lr;
        if (col < NROLL)
          recon[(size_t)b * (T_SZ * NROLL) + t * NROLL + col] = acc[j][q] + bo[j] - lz;
      }
    }
  }
}

// ---------------- host ----------------
extern "C" void kernel_launch(void* const* d_in, const int* in_sizes, int n_in,
                              void* d_out, int out_size, void* d_ws, size_t ws_size,
                              hipStream_t stream) {
  const float* z1    = (const float*)d_in[0];
  const float* d1m   = (const float*)d_in[1];
  const float* d1s   = (const float*)d_in[2];
  const float* d2m   = (const float*)d_in[3];
  const float* d2s   = (const float*)d_in[4];
  const float* rhy   = (const float*)d_in[5];
  const float* cond  = (const float*)d_in[7];
  const float* w_ih1 = (const float*)d_in[9];
  const float* w_hh1 = (const float*)d_in[10];
  const float* b_ih1 = (const float*)d_in[11];
  const float* b_hh1 = (const float*)d_in[12];
  const float* w_ih2 = (const float*)d_in[13];
  const float* w_hh2 = (const float*)d_in[14];
  const float* b_ih2 = (const float*)d_in[15];
  const float* b_hh2 = (const float*)d_in[16];
  const float* w_init = (const float*)d_in[17];
  const float* b_init = (const float*)d_in[18];
  const float* w_out  = (const float*)d_in[19];
  const float* b_out  = (const float*)d_in[20];
  float* out = (float*)d_out;

  char* ws = (char*)d_ws;
  size_t off = 0;
  auto alloc = [&](size_t bytes) -> void* {
    off = (off + 255) & ~(size_t)255;
    void* p = ws + off;
    off += bytes;
    return p;
  };
  u16* whh1_b = (u16*)alloc((size_t)3072 * 1024 * 2);
  u16* wih2_b = (u16*)alloc((size_t)3072 * 1024 * 2);
  u16* whh2_b = (u16*)alloc((size_t)3072 * 1024 * 2);
  u16* wout_b = (u16*)alloc((size_t)NCPAD * 1024 * 2);
  u16* wext_b = (u16*)alloc((size_t)3072 * EXTK * 2);
  float* wih1T = (float*)alloc((size_t)NROLL * 3072 * 4);
  u16* aext   = (u16*)alloc((size_t)T_SZ * B_SZ * EXTK * 2);
  float* h1f  = (float*)alloc((size_t)B_SZ * H_SZ * 4);
  float* h2f  = (float*)alloc((size_t)B_SZ * H_SZ * 4);
  u16* h1b[2];
  h1b[0] = (u16*)alloc((size_t)B_SZ * H_SZ * 2);
  h1b[1] = (u16*)alloc((size_t)B_SZ * H_SZ * 2);
  u16* h2b[2];
  h2b[0] = (u16*)alloc((size_t)B_SZ * H_SZ * 2);
  h2b[1] = (u16*)alloc((size_t)B_SZ * H_SZ * 2);
  int* amax = (int*)alloc((size_t)B_SZ * 4);
  u16* z1b    = (u16*)alloc((size_t)B_SZ * 128 * 2);
  u16* winitb = (u16*)alloc((size_t)H_SZ * 128 * 2);

  const int NW = 3072 * 1024;
  cvt_kernel<<<(NW + 255) / 256, 256, 0, stream>>>(w_hh1, whh1_b, NW);
  cvt_kernel<<<(NW + 255) / 256, 256, 0, stream>>>(w_ih2, wih2_b, NW);
  cvt_kernel<<<(NW + 255) / 256, 256, 0, stream>>>(w_hh2, whh2_b, NW);
  cvt_kernel<<<(B_SZ * 128 + 255) / 256, 256, 0, stream>>>(z1, z1b, B_SZ * 128);
  cvt_kernel<<<(H_SZ * 128 + 255) / 256, 256, 0, stream>>>(w_init, winitb, H_SZ * 128);
  build_wout_kernel<<<(NCPAD * 1024) / 256, 256, 0, stream>>>(w_out, wout_b);
  build_wext_kernel<<<(3072 * EXTK) / 256, 256, 0, stream>>>(w_ih1, wext_b);
  build_wih1T_kernel<<<(NROLL * 3072 + 255) / 256, 256, 0, stream>>>(w_ih1, wih1T);
  build_aext_kernel<<<(T_SZ * B_SZ * EXTK) / 256, 256, 0, stream>>>(rhy, cond, z1, aext);
  init_h1_mfma_kernel<<<dim3(B_SZ / 128, H_SZ / 64), 256, 0, stream>>>(z1b, winitb, b_init, h1f, h1b[0]);
  init_amax_kernel<<<B_SZ / 256, 256, 0, stream>>>(amax);

  // passthrough outputs 1..5
  size_t o_rhy = (size_t)B_SZ * T_SZ * NROLL;
  size_t o_d1m = o_rhy + (size_t)B_SZ * T_SZ * 3;
  size_t o_d1s = o_d1m + (size_t)B_SZ * 128;
  size_t o_d2m = o_d1s + (size_t)B_SZ * 128;
  size_t o_d2s = o_d2m + (size_t)B_SZ * 128;
  hipMemcpyAsync(out + o_rhy, rhy, (size_t)B_SZ * T_SZ * 3 * 4, hipMemcpyDeviceToDevice, stream);
  hipMemcpyAsync(out + o_d1m, d1m, (size_t)B_SZ * 128 * 4, hipMemcpyDeviceToDevice, stream);
  hipMemcpyAsync(out + o_d1s, d1s, (size_t)B_SZ * 128 * 4, hipMemcpyDeviceToDevice, stream);
  hipMemcpyAsync(out + o_d2m, d2m, (size_t)B_SZ * 128 * 4, hipMemcpyDeviceToDevice, stream);
  hipMemcpyAsync(out + o_d2s, d2s, (size_t)B_SZ * 128 * 4, hipMemcpyDeviceToDevice, stream);

  dim3 g1grid(B_SZ / 128, H_SZ / 64);
  dim3 g2grid(B_SZ / 64, H_SZ / 64);
  for (int t = 0; t < T_SZ; ++t) {
    const u16* h1in = h1b[t & 1];
    u16* h1out = h1b[(t & 1) ^ 1];
    gru1_kernel<<<g1grid, 256, 0, stream>>>(h1in, whh1_b, aext + (size_t)t * B_SZ * EXTK,
                                            wext_b, wih1T, b_ih1, b_hh1, amax, h1f, h1out);
    const u16* h2in = (t == 0) ? (const u16*)h1out : h2b[t & 1];
    const float* hpf = (t == 0) ? h1f : h2f;
    u16* h2out = h2b[(t & 1) ^ 1];
    gru2_kernel<<<g2grid, 256, 0, stream>>>(h1out, h2in, wih2_b, whh2_b, b_ih2, b_hh2,
                                            hpf, h2f, h2out);
    out_kernel<<<B_SZ / 16, 128, 0, stream>>>(h2out, wout_b, b_out, out, amax, t);
  }
  (void)in_sizes; (void)n_in; (void)out_size; (void)ws_size;
}

// Round 14
// 3631.696 us; speedup vs baseline: 1.0807x; 1.0807x over previous
//
#include <hip/hip_runtime.h>
#include <stdint.h>

typedef unsigned short u16;
typedef unsigned int u32;
typedef __attribute__((ext_vector_type(4))) float f32x4;
typedef __attribute__((ext_vector_type(8))) short short8;

#define MFMA16(a, b, c) __builtin_amdgcn_mfma_f32_16x16x32_bf16(a, b, c, 0, 0, 0)

// ---------- sizes ----------
#define B_SZ   4096
#define H_SZ   1024
#define T_SZ   32
#define NROLL  130
#define NCPAD  144   // 130 padded to 9x16

__device__ __forceinline__ u16 f2b(float f) {
  u32 u = __float_as_uint(f);
  u += 0x7FFFu + ((u >> 16) & 1u);
  return (u16)(u >> 16);
}
__device__ __forceinline__ float sigm(float x) { return 1.f / (1.f + __expf(-x)); }

// async global->LDS (16B). LDS dest = wave-uniform base + lane*16 (linear).
__device__ __forceinline__ void gld16(const void* g, const void* lds) {
  __builtin_amdgcn_global_load_lds(
      (const __attribute__((address_space(1))) u32*)(uintptr_t)g,
      (__attribute__((address_space(3))) u32*)(u32)(uintptr_t)lds, 16, 0, 0);
}

// ---------------- setup kernels ----------------
__global__ void cvt_kernel(const float* __restrict__ s, u16* __restrict__ d, int n) {
  int i = blockIdx.x * 256 + threadIdx.x;
  if (i < n) d[i] = f2b(s[i]);
}

__global__ void build_wout_kernel(const float* __restrict__ w, u16* __restrict__ d) {
  int i = blockIdx.x * 256 + threadIdx.x;           // 144*1024
  int r = i >> 10, c = i & 1023;
  d[i] = f2b(r < NROLL ? w[r * H_SZ + c] : 0.f);
}

// Wz1[j][k] = w_ih1[j][133+k], j in 0..3071, k in 0..127 (z1 slice, all 3 gates)
__global__ void build_wz1_kernel(const float* __restrict__ w, u16* __restrict__ d) {
  int i = blockIdx.x * 256 + threadIdx.x;           // 3072*128
  int j = i >> 7, k = i & 127;
  d[i] = f2b(w[j * 273 + 133 + k]);
}

// W15[j][k]: k<3 -> rhy cols (130+k); k<15 -> cond cols (261+k-3); else 0. [3072][32]
__global__ void build_wext15_kernel(const float* __restrict__ w, u16* __restrict__ d) {
  int i = blockIdx.x * 256 + threadIdx.x;           // 3072*32
  int j = i >> 5, k = i & 31;
  float v = 0.f;
  if (k < 3)       v = w[j * 273 + 130 + k];
  else if (k < 15) v = w[j * 273 + 261 + (k - 3)];
  d[i] = f2b(v);
}

// A15[t][b][k]: k<3 -> rhy[b][t][k]; k<15 -> cond[b][t][k-3]; else 0. [32][4096][32]
__global__ void build_aext15_kernel(const float* __restrict__ rhy, const float* __restrict__ cond,
                                    u16* __restrict__ d) {
  int i = blockIdx.x * 256 + threadIdx.x;           // 32*4096*32 = 4194304
  int k = i & 31;
  int b = (i >> 5) & 4095;
  int t = i >> 17;
  float v = 0.f;
  if (k < 3)       v = rhy[b * (T_SZ * 3) + t * 3 + k];
  else if (k < 15) v = cond[b * (T_SZ * 12) + t * 12 + (k - 3)];
  d[i] = f2b(v);
}

// wih1T[c][j] = w_ih1[j][c] for c < 130 (one-hot gather rows, f32)
__global__ void build_wih1T_kernel(const float* __restrict__ w, float* __restrict__ d) {
  int i = blockIdx.x * 256 + threadIdx.x;           // 130*3072
  if (i >= NROLL * 3072) return;
  int c = i / 3072, j = i % 3072;
  d[i] = w[j * 273 + c];
}

__global__ void init_amax_kernel(int* __restrict__ a) {
  a[blockIdx.x * 256 + threadIdx.x] = NROLL - 1;  // one-hot at last col
}

// bext[b][j] = sum_k z1[b][k] * Wz1[j][k]  (f32 out, no bias). 128x64 tile, K=128.
__global__ __launch_bounds__(256, 2)
void bext_kernel(const u16* __restrict__ Az,   // z1 bf16 [4096][128]
                 const u16* __restrict__ Wz,   // Wz1 bf16 [3072][128]
                 float* __restrict__ bext) {
  __shared__ u16 As[128 * 64];
  __shared__ u16 Ws[64 * 64];
  const int tid = threadIdx.x;
  const int lane = tid & 63, wv = tid >> 6;
  const int wm = wv >> 1, wn = wv & 1;
  const int lr = lane & 15, lk = lane >> 4;
  const int Mbase = blockIdx.x * 128, Nbase = blockIdx.y * 64;

  f32x4 zero = {0.f, 0.f, 0.f, 0.f};
  f32x4 acc[4][2];
#pragma unroll
  for (int m = 0; m < 4; ++m)
#pragma unroll
    for (int n = 0; n < 2; ++n) acc[m][n] = zero;

  for (int it = 0; it < 2; ++it) {
#pragma unroll
    for (int i = 0; i < 4; ++i) {
      int seg = i * 256 + tid, row = seg >> 3, c8 = seg & 7;
      gld16(Az + (size_t)(Mbase + row) * 128 + it * 64 + c8 * 8, As + ((i * 256 + (wv << 6)) << 3));
    }
#pragma unroll
    for (int i = 0; i < 2; ++i) {
      int seg = i * 256 + tid, row = seg >> 3, c8 = seg & 7;
      gld16(Wz + (size_t)(Nbase + row) * 128 + it * 64 + c8 * 8, Ws + ((i * 256 + (wv << 6)) << 3));
    }
    __syncthreads();
#pragma unroll
    for (int kk = 0; kk < 2; ++kk) {
      short8 af[4];
#pragma unroll
      for (int m = 0; m < 4; ++m)
        af[m] = *(const short8*)(As + (((wm << 6) + (m << 4) + lr) << 6) + kk * 32 + (lk << 3));
      short8 bw[2];
#pragma unroll
      for (int n = 0; n < 2; ++n)
        bw[n] = *(const short8*)(Ws + ((((wn << 5) + (n << 4) + lr)) << 6) + kk * 32 + (lk << 3));
#pragma unroll
      for (int m = 0; m < 4; ++m)
#pragma unroll
        for (int n = 0; n < 2; ++n)
          acc[m][n] = MFMA16(af[m], bw[n], acc[m][n]);
    }
    __syncthreads();
  }

  int jcol[2];
  jcol[0] = Nbase + (wn << 5) + lr;
  jcol[1] = jcol[0] + 16;
#pragma unroll
  for (int m = 0; m < 4; ++m) {
#pragma unroll
    for (int q = 0; q < 4; ++q) {
      int b = Mbase + (wm << 6) + (m << 4) + (lk << 2) + q;
#pragma unroll
      for (int n = 0; n < 2; ++n)
        bext[(size_t)b * 3072 + jcol[n]] = acc[m][n][q];
    }
  }
}

// h1_0 = tanh(z1 @ w_init^T + b_init), MFMA.
__global__ __launch_bounds__(256, 2)
void init_h1_mfma_kernel(const u16* __restrict__ Az,  // z1 bf16 [4096][128]
                         const u16* __restrict__ Wz,  // w_init bf16 [1024][128]
                         const float* __restrict__ b_init,
                         float* __restrict__ h1f, u16* __restrict__ h1b) {
  __shared__ u16 As[128 * 64];
  __shared__ u16 Ws[64 * 64];
  const int tid = threadIdx.x;
  const int lane = tid & 63, wv = tid >> 6;
  const int wm = wv >> 1, wn = wv & 1;
  const int lr = lane & 15, lk = lane >> 4;
  const int Mbase = blockIdx.x * 128, Nbase = blockIdx.y * 64;

  f32x4 zero = {0.f, 0.f, 0.f, 0.f};
  f32x4 acc[4][2];
#pragma unroll
  for (int m = 0; m < 4; ++m)
#pragma unroll
    for (int n = 0; n < 2; ++n) acc[m][n] = zero;

  for (int it = 0; it < 2; ++it) {
#pragma unroll
    for (int i = 0; i < 4; ++i) {
      int seg = i * 256 + tid, row = seg >> 3, c8 = seg & 7;
      gld16(Az + (size_t)(Mbase + row) * 128 + it * 64 + c8 * 8, As + ((i * 256 + (wv << 6)) << 3));
    }
#pragma unroll
    for (int i = 0; i < 2; ++i) {
      int seg = i * 256 + tid, row = seg >> 3, c8 = seg & 7;
      gld16(Wz + (size_t)(Nbase + row) * 128 + it * 64 + c8 * 8, Ws + ((i * 256 + (wv << 6)) << 3));
    }
    __syncthreads();
#pragma unroll
    for (int kk = 0; kk < 2; ++kk) {
      short8 af[4];
#pragma unroll
      for (int m = 0; m < 4; ++m)
        af[m] = *(const short8*)(As + (((wm << 6) + (m << 4) + lr) << 6) + kk * 32 + (lk << 3));
      short8 bw[2];
#pragma unroll
      for (int n = 0; n < 2; ++n)
        bw[n] = *(const short8*)(Ws + ((((wn << 5) + (n << 4) + lr)) << 6) + kk * 32 + (lk << 3));
#pragma unroll
      for (int m = 0; m < 4; ++m)
#pragma unroll
        for (int n = 0; n < 2; ++n)
          acc[m][n] = MFMA16(af[m], bw[n], acc[m][n]);
    }
    __syncthreads();
  }

  int hcol[2];
  hcol[0] = Nbase + (wn << 5) + lr;
  hcol[1] = hcol[0] + 16;
#pragma unroll
  for (int m = 0; m < 4; ++m) {
#pragma unroll
    for (int q = 0; q < 4; ++q) {
      int b = Mbase + (wm << 6) + (m << 4) + (lk << 2) + q;
      size_t ho = (size_t)b << 10;
#pragma unroll
      for (int n = 0; n < 2; ++n) {
        int h = hcol[n];
        float v = tanhf(acc[m][n][q] + b_init[h]);
        h1f[ho + h] = v;
        h1b[ho + h] = f2b(v);
      }
    }
  }
}

// ---- GRU cell 1: 8x BK=128 main + 1x BK=32 rhy/cond mini-iter + bext epilogue ----
__global__ __launch_bounds__(256, 2)
void gru1_kernel(const u16* __restrict__ Ah,   // h1 bf16 [B][1024]
                 const u16* __restrict__ Whh,  // w_hh1 bf16 [3072][1024]
                 const u16* __restrict__ A15,  // rhy/cond bf16 [B][32] (this t)
                 const u16* __restrict__ W15,  // bf16 [3072][32]
                 const float* __restrict__ bext, // z1-part gi [B][3072] f32
                 const float* __restrict__ gT, // w_ih1T [130][3072]
                 const float* __restrict__ bih, const float* __restrict__ bhh,
                 const int* __restrict__ amax,
                 float* __restrict__ h1f, u16* __restrict__ h1o) {
  __shared__ u16 smem[40960];   // 80 KB: As 128x128 (32KB) + Ws 192x128 (48KB)
  u16* As = smem;
  u16* Wsm = smem + 16384;
  const int tid = threadIdx.x;
  const int lane = tid & 63, wv = tid >> 6;
  const int wm = wv >> 1, wn = wv & 1;
  const int lr = lane & 15, lk = lane >> 4;
  const int Mbase = blockIdx.x * 128, Nbase = blockIdx.y * 64;

  f32x4 zero = {0.f, 0.f, 0.f, 0.f};
  f32x4 acc_r[4][2], acc_z[4][2], acc_hn[4][2], acc_in[4][2];
#pragma unroll
  for (int m = 0; m < 4; ++m)
#pragma unroll
    for (int n = 0; n < 2; ++n) { acc_r[m][n] = zero; acc_z[m][n] = zero; acc_hn[m][n] = zero; acc_in[m][n] = zero; }

  // ---- main phase: K=1024 in 8 iters of BK=128 ----
#pragma unroll 1
  for (int it = 0; it < 8; ++it) {
#pragma unroll
    for (int i = 0; i < 8; ++i) {     // A: 128 rows x 128 cols
      int seg = i * 256 + tid, row = seg >> 4, c16 = (seg & 15) ^ (row & 7);
      gld16(Ah + (size_t)(Mbase + row) * 1024 + it * 128 + c16 * 8, As + ((i * 256 + (wv << 6)) << 3));
    }
#pragma unroll
    for (int i = 0; i < 12; ++i) {    // W: 192 rows x 128 cols
      int seg = i * 256 + tid, gr = seg >> 4, c16 = (seg & 15) ^ (gr & 7);
      int gg = gr >> 6, r = gr & 63;
      gld16(Whh + ((size_t)(gg << 10) + Nbase + r) * 1024 + it * 128 + c16 * 8,
            Wsm + ((i * 256 + (wv << 6)) << 3));
    }
    __syncthreads();
    __builtin_amdgcn_s_setprio(1);
#pragma unroll
    for (int kk = 0; kk < 4; ++kk) {
      int gc = (kk << 2) + lk;        // global chunk16 wanted
      short8 af[4];
#pragma unroll
      for (int m = 0; m < 4; ++m) {
        int row = (wm << 6) + (m << 4) + lr;
        af[m] = *(const short8*)(As + (row << 7) + ((gc ^ (row & 7)) << 3));
      }
      short8 bw[3][2];
#pragma unroll
      for (int g = 0; g < 3; ++g)
#pragma unroll
        for (int n = 0; n < 2; ++n) {
          int row = (g << 6) + (wn << 5) + (n << 4) + lr;
          bw[g][n] = *(const short8*)(Wsm + (row << 7) + ((gc ^ (row & 7)) << 3));
        }
#pragma unroll
      for (int m = 0; m < 4; ++m)
#pragma unroll
        for (int n = 0; n < 2; ++n) {
          acc_r[m][n] = MFMA16(af[m], bw[0][n], acc_r[m][n]);
          acc_z[m][n] = MFMA16(af[m], bw[1][n], acc_z[m][n]);
          acc_hn[m][n] = MFMA16(af[m], bw[2][n], acc_hn[m][n]);
        }
    }
    __builtin_amdgcn_s_setprio(0);
    __syncthreads();
  }

  // ---- mini ext iter: K=32 (rhy 3 + cond 12, zero-padded) ----
  {
#pragma unroll
    for (int i = 0; i < 2; ++i) {     // A15: 128 rows x 4 chunks
      int seg = i * 256 + tid, row = seg >> 2, c4 = (seg & 3) ^ (row & 3);
      gld16(A15 + (size_t)(Mbase + row) * 32 + c4 * 8, As + ((i * 256 + (wv << 6)) << 3));
    }
#pragma unroll
    for (int i = 0; i < 3; ++i) {     // W15: 192 rows x 4 chunks
      int seg = i * 256 + tid, gr = seg >> 2, c4 = (seg & 3) ^ (gr & 3);
      int gg = gr >> 6, r = gr & 63;
      gld16(W15 + ((size_t)(gg << 10) + Nbase + r) * 32 + c4 * 8,
            Wsm + ((i * 256 + (wv << 6)) << 3));
    }
    __syncthreads();
    __builtin_amdgcn_s_setprio(1);
    short8 af[4];
#pragma unroll
    for (int m = 0; m < 4; ++m) {
      int row = (wm << 6) + (m << 4) + lr;
      af[m] = *(const short8*)(As + (row << 5) + (((lk) ^ (row & 3)) << 3));
    }
    short8 bw[3][2];
#pragma unroll
    for (int g = 0; g < 3; ++g)
#pragma unroll
      for (int n = 0; n < 2; ++n) {
        int row = (g << 6) + (wn << 5) + (n << 4) + lr;
        bw[g][n] = *(const short8*)(Wsm + (row << 5) + (((lk) ^ (row & 3)) << 3));
      }
#pragma unroll
    for (int m = 0; m < 4; ++m)
#pragma unroll
      for (int n = 0; n < 2; ++n) {
        acc_r[m][n] = MFMA16(af[m], bw[0][n], acc_r[m][n]);
        acc_z[m][n] = MFMA16(af[m], bw[1][n], acc_z[m][n]);
        acc_in[m][n] = MFMA16(af[m], bw[2][n], acc_in[m][n]);
      }
    __builtin_amdgcn_s_setprio(0);
    __syncthreads();
  }

  // epilogue: + bias + bext(z1 part) + one-hot gather, GRU nonlinearity
  int hcol[2];
  hcol[0] = Nbase + (wn << 5) + lr;
  hcol[1] = hcol[0] + 16;
  float bi0[2], bi1[2], bi2[2], bh0[2], bh1[2], bh2[2];
#pragma unroll
  for (int n = 0; n < 2; ++n) {
    int h = hcol[n];
    bi0[n] = bih[h]; bi1[n] = bih[1024 + h]; bi2[n] = bih[2048 + h];
    bh0[n] = bhh[h]; bh1[n] = bhh[1024 + h]; bh2[n] = bhh[2048 + h];
  }
#pragma unroll
  for (int m = 0; m < 4; ++m) {
#pragma unroll
    for (int q = 0; q < 4; ++q) {
      int b = Mbase + (wm << 6) + (m << 4) + (lk << 2) + q;
      const float* gRow = gT + (size_t)amax[b] * 3072;
      const float* bx = bext + (size_t)b * 3072;
      size_t ho = (size_t)b << 10;
#pragma unroll
      for (int n = 0; n < 2; ++n) {
        int h = hcol[n];
        float rp = acc_r[m][n][q] + bi0[n] + bh0[n] + gRow[h] + bx[h];
        float zp = acc_z[m][n][q] + bi1[n] + bh1[n] + gRow[1024 + h] + bx[1024 + h];
        float inp = acc_in[m][n][q] + bi2[n] + gRow[2048 + h] + bx[2048 + h];
        float hnp = acc_hn[m][n][q] + bh2[n];
        float r = sigm(rp), z = sigm(zp);
        float nn = tanhf(inp + r * hnp);
        float hv = (1.f - z) * nn + z * h1f[ho + h];
        h1f[ho + h] = hv;
        h1o[ho + h] = f2b(hv);
      }
    }
  }
}

// ---- GRU cell 2 (fused gi2+gh2): lockstep BK=64, XOR chunk swizzle, T5 setprio (R9) ----
__global__ __launch_bounds__(256, 2)
void gru2_kernel(const u16* __restrict__ A1,  // h1_new bf16
                 const u16* __restrict__ A2,  // h2_prev bf16 (h1_new at t=0)
                 const u16* __restrict__ Wi,  // w_ih2 bf16
                 const u16* __restrict__ Wh,  // w_hh2 bf16
                 const float* __restrict__ bih, const float* __restrict__ bhh,
                 const float* __restrict__ hpf,  // h2_prev f32 (h1f at t=0)
                 float* __restrict__ h2f, u16* __restrict__ h2o) {
  __shared__ u16 As1[128 * 64];
  __shared__ u16 As2[128 * 64];
  __shared__ u16 Ws[384 * 64];
  const int tid = threadIdx.x;
  const int lane = tid & 63, wv = tid >> 6;
  const int wm = wv >> 1, wn = wv & 1;
  const int lr = lane & 15, lk = lane >> 4;
  const int Mbase = blockIdx.x * 128, Nbase = blockIdx.y * 64;

  f32x4 zero = {0.f, 0.f, 0.f, 0.f};
  f32x4 acc_r[4][2], acc_z[4][2], acc_hn[4][2], acc_in[4][2];
#pragma unroll
  for (int m = 0; m < 4; ++m)
#pragma unroll
    for (int n = 0; n < 2; ++n) { acc_r[m][n] = zero; acc_z[m][n] = zero; acc_hn[m][n] = zero; acc_in[m][n] = zero; }

#pragma unroll 1
  for (int it = 0; it < 16; ++it) {
#pragma unroll
    for (int i = 0; i < 4; ++i) {
      int seg = i * 256 + tid, row = seg >> 3, c8 = (seg & 7) ^ (row & 7);
      size_t go = (size_t)(Mbase + row) * 1024 + it * 64 + c8 * 8;
      gld16(A1 + go, As1 + ((i * 256 + (wv << 6)) << 3));
      gld16(A2 + go, As2 + ((i * 256 + (wv << 6)) << 3));
    }
#pragma unroll
    for (int i = 0; i < 12; ++i) {
      int seg = i * 256 + tid, gr = seg >> 3, c8 = (seg & 7) ^ (gr & 7);
      int s = gr >> 6, r = gr & 63;
      const u16* Wm = (s < 3) ? Wi : Wh;
      int gate = (s < 3) ? s : (s - 3);
      gld16(Wm + ((size_t)(gate << 10) + Nbase + r) * 1024 + it * 64 + c8 * 8,
            Ws + ((i * 256 + (wv << 6)) << 3));
    }
    __syncthreads();
    __builtin_amdgcn_s_setprio(1);
#pragma unroll
    for (int kk = 0; kk < 2; ++kk) {
      int gc = (kk << 2) + lk;
      short8 a1[4], a2[4];
#pragma unroll
      for (int m = 0; m < 4; ++m) {
        int row = (wm << 6) + (m << 4) + lr;
        int off = (row << 6) + ((gc ^ (row & 7)) << 3);
        a1[m] = *(const short8*)(As1 + off);
        a2[m] = *(const short8*)(As2 + off);
      }
      short8 bw[6][2];
#pragma unroll
      for (int s = 0; s < 6; ++s)
#pragma unroll
        for (int n = 0; n < 2; ++n) {
          int row = (s << 6) + (wn << 5) + (n << 4) + lr;
          bw[s][n] = *(const short8*)(Ws + (row << 6) + ((gc ^ (row & 7)) << 3));
        }
#pragma unroll
      for (int m = 0; m < 4; ++m)
#pragma unroll
        for (int n = 0; n < 2; ++n) {
          acc_r[m][n] = MFMA16(a1[m], bw[0][n], acc_r[m][n]);
          acc_r[m][n] = MFMA16(a2[m], bw[3][n], acc_r[m][n]);
          acc_z[m][n] = MFMA16(a1[m], bw[1][n], acc_z[m][n]);
          acc_z[m][n] = MFMA16(a2[m], bw[4][n], acc_z[m][n]);
          acc_in[m][n] = MFMA16(a1[m], bw[2][n], acc_in[m][n]);
          acc_hn[m][n] = MFMA16(a2[m], bw[5][n], acc_hn[m][n]);
        }
    }
    __builtin_amdgcn_s_setprio(0);
    __syncthreads();
  }

  int hcol[2];
  hcol[0] = Nbase + (wn << 5) + lr;
  hcol[1] = hcol[0] + 16;
  float bi0[2], bi1[2], bi2[2], bh0[2], bh1[2], bh2[2];
#pragma unroll
  for (int n = 0; n < 2; ++n) {
    int h = hcol[n];
    bi0[n] = bih[h]; bi1[n] = bih[1024 + h]; bi2[n] = bih[2048 + h];
    bh0[n] = bhh[h]; bh1[n] = bhh[1024 + h]; bh2[n] = bhh[2048 + h];
  }
#pragma unroll
  for (int m = 0; m < 4; ++m) {
#pragma unroll
    for (int q = 0; q < 4; ++q) {
      int b = Mbase + (wm << 6) + (m << 4) + (lk << 2) + q;
      size_t ho = (size_t)b << 10;
#pragma unroll
      for (int n = 0; n < 2; ++n) {
        int h = hcol[n];
        float r = sigm(acc_r[m][n][q] + bi0[n] + bh0[n]);
        float z = sigm(acc_z[m][n][q] + bi1[n] + bh1[n]);
        float nn = tanhf(acc_in[m][n][q] + bi2[n] + r * (acc_hn[m][n][q] + bh2[n]));
        float hv = (1.f - z) * nn + z * hpf[ho + h];
        h2f[ho + h] = hv;
        h2o[ho + h] = f2b(hv);
      }
    }
  }
}

// ---- logits + log_softmax + argmax: 256 blocks x 128 threads, BK=128 (8 drains) ----
__global__ __launch_bounds__(128)
void out_kernel(const u16* __restrict__ A,   // h2_new bf16
                const u16* __restrict__ W,   // wout bf16 [144][1024]
                const float* __restrict__ b_out,
                float* __restrict__ recon, int* __restrict__ amax_out, int t) {
  __shared__ u16 As[16 * 128];   // 4 KB
  __shared__ u16 Ws[144 * 128];  // 36 KB
  __shared__ float redm[2][16], reds[2][16], logZs[16];
  __shared__ int redi[2][16];
  const int tid = threadIdx.x;
  const int lane = tid & 63, wv = tid >> 6;   // 2 waves
  const int lr = lane & 15, lk = lane >> 4;
  const int bb = blockIdx.x;  // 16 rows each
  const int nf0 = wv ? 5 : 0;                 // first owned frag
  const int nfn = wv ? 4 : 5;                 // owned frag count

  f32x4 zero = {0.f, 0.f, 0.f, 0.f};
  f32x4 acc[5];
#pragma unroll
  for (int j = 0; j < 5; ++j) acc[j] = zero;

  float bo[5];
#pragma unroll
  for (int j = 0; j < 5; ++j) {
    int col = ((nf0 + j) << 4) + lr;
    bo[j] = (j < nfn && col < NROLL) ? b_out[col] : -1e30f;
  }

#pragma unroll 1
  for (int it = 0; it < 8; ++it) {
#pragma unroll
    for (int i = 0; i < 2; ++i) {  // A: 16 x 128
      int seg = i * 128 + tid, row = seg >> 4, c16 = seg & 15;
      gld16(A + (size_t)(bb * 16 + row) * 1024 + it * 128 + c16 * 8, As + ((i * 128 + (wv << 6)) << 3));
    }
#pragma unroll
    for (int i = 0; i < 18; ++i) { // W: 144 x 128
      int seg = i * 128 + tid, row = seg >> 4, c16 = seg & 15;
      gld16(W + (size_t)row * 1024 + it * 128 + c16 * 8, Ws + ((i * 128 + (wv << 6)) << 3));
    }
    __syncthreads();
#pragma unroll
    for (int kk = 0; kk < 4; ++kk) {
      short8 af = *(const short8*)(As + (lr << 7) + kk * 32 + (lk << 3));
#pragma unroll 5
      for (int j = 0; j < 5; ++j) {
        if (j < nfn) {
          short8 bw = *(const short8*)(Ws + ((((nf0 + j) << 4) + lr) << 7) + kk * 32 + (lk << 3));
          acc[j] = MFMA16(af, bw, acc[j]);
        }
      }
    }
    __syncthreads();
  }

#pragma unroll
  for (int q = 0; q < 4; ++q) {
    int r = (lk << 2) + q;
    float vmax = -1e30f; int vidx = 0;
#pragma unroll 5
    for (int j = 0; j < 5; ++j) {
      if (j < nfn) {
        int col = ((nf0 + j) << 4) + lr;
        float x = acc[j][q] + bo[j];
        if (x > vmax) { vmax = x; vidx = col; }
      }
    }
    for (int d = 1; d < 16; d <<= 1) {
      float om = __shfl_xor(vmax, d);
      int oi = __shfl_xor(vidx, d);
      if (om > vmax || (om == vmax && oi < vidx)) { vmax = om; vidx = oi; }
    }
    float s = 0.f;
#pragma unroll 5
    for (int j = 0; j < 5; ++j) {
      if (j < nfn) s += __expf(acc[j][q] + bo[j] - vmax);
    }
    for (int d = 1; d < 16; d <<= 1) s += __shfl_xor(s, d);
    if (lr == 0) { redm[wv][r] = vmax; reds[wv][r] = s; redi[wv][r] = vidx; }
  }
  __syncthreads();

  if (tid < 16) {
    float m0 = redm[0][tid], m1 = redm[1][tid];
    float s0 = reds[0][tid], s1 = reds[1][tid];
    float M = fmaxf(m0, m1);
    float S = s0 * __expf(m0 - M) + s1 * __expf(m1 - M);
    logZs[tid] = M + __logf(S);
    amax_out[bb * 16 + tid] = (m1 > m0) ? redi[1][tid] : redi[0][tid];
  }
  __syncthreads();

#pragma unroll
  for (int q = 0; q < 4; ++q) {
    int r = (lk << 2) + q;
    int b = bb * 16 + r;
    float lz = logZs[r];
#pragma unroll 5
    for (int j = 0; j < 5; ++j) {
      if (j < nfn) {
        int col = ((nf0 + j) << 4) + lr;
        if (col < NROLL)
          recon[(size_t)b * (T_SZ * NROLL) + t * NROLL + col] = acc[j][q] + bo[j] - lz;
      }
    }
  }
}

// ---------------- host ----------------
extern "C" void kernel_launch(void* const* d_in, const int* in_sizes, int n_in,
                              void* d_out, int out_size, void* d_ws, size_t ws_size,
                              hipStream_t stream) {
  const float* z1    = (const float*)d_in[0];
  const float* d1m   = (const float*)d_in[1];
  const float* d1s   = (const float*)d_in[2];
  const float* d2m   = (const float*)d_in[3];
  const float* d2s   = (const float*)d_in[4];
  const float* rhy   = (const float*)d_in[5];
  const float* cond  = (const float*)d_in[7];
  const float* w_ih1 = (const float*)d_in[9];
  const float* w_hh1 = (const float*)d_in[10];
  const float* b_ih1 = (const float*)d_in[11];
  const float* b_hh1 = (const float*)d_in[12];
  const float* w_ih2 = (const float*)d_in[13];
  const float* w_hh2 = (const float*)d_in[14];
  const float* b_ih2 = (const float*)d_in[15];
  const float* b_hh2 = (const float*)d_in[16];
  const float* w_init = (const float*)d_in[17];
  const float* b_init = (const float*)d_in[18];
  const float* w_out  = (const float*)d_in[19];
  const float* b_out  = (const float*)d_in[20];
  float* out = (float*)d_out;

  char* ws = (char*)d_ws;
  size_t off = 0;
  auto alloc = [&](size_t bytes) -> void* {
    off = (off + 255) & ~(size_t)255;
    void* p = ws + off;
    off += bytes;
    return p;
  };
  u16* whh1_b = (u16*)alloc((size_t)3072 * 1024 * 2);
  u16* wih2_b = (u16*)alloc((size_t)3072 * 1024 * 2);
  u16* whh2_b = (u16*)alloc((size_t)3072 * 1024 * 2);
  u16* wout_b = (u16*)alloc((size_t)NCPAD * 1024 * 2);
  u16* wz1_b  = (u16*)alloc((size_t)3072 * 128 * 2);
  u16* w15_b  = (u16*)alloc((size_t)3072 * 32 * 2);
  u16* a15    = (u16*)alloc((size_t)T_SZ * B_SZ * 32 * 2);
  float* bext = (float*)alloc((size_t)B_SZ * 3072 * 4);
  float* wih1T = (float*)alloc((size_t)NROLL * 3072 * 4);
  float* h1f  = (float*)alloc((size_t)B_SZ * H_SZ * 4);
  float* h2f  = (float*)alloc((size_t)B_SZ * H_SZ * 4);
  u16* h1b[2];
  h1b[0] = (u16*)alloc((size_t)B_SZ * H_SZ * 2);
  h1b[1] = (u16*)alloc((size_t)B_SZ * H_SZ * 2);
  u16* h2b[2];
  h2b[0] = (u16*)alloc((size_t)B_SZ * H_SZ * 2);
  h2b[1] = (u16*)alloc((size_t)B_SZ * H_SZ * 2);
  int* amax = (int*)alloc((size_t)B_SZ * 4);
  u16* z1b    = (u16*)alloc((size_t)B_SZ * 128 * 2);
  u16* winitb = (u16*)alloc((size_t)H_SZ * 128 * 2);

  const int NW = 3072 * 1024;
  cvt_kernel<<<(NW + 255) / 256, 256, 0, stream>>>(w_hh1, whh1_b, NW);
  cvt_kernel<<<(NW + 255) / 256, 256, 0, stream>>>(w_ih2, wih2_b, NW);
  cvt_kernel<<<(NW + 255) / 256, 256, 0, stream>>>(w_hh2, whh2_b, NW);
  cvt_kernel<<<(B_SZ * 128 + 255) / 256, 256, 0, stream>>>(z1, z1b, B_SZ * 128);
  cvt_kernel<<<(H_SZ * 128 + 255) / 256, 256, 0, stream>>>(w_init, winitb, H_SZ * 128);
  build_wout_kernel<<<(NCPAD * 1024) / 256, 256, 0, stream>>>(w_out, wout_b);
  build_wz1_kernel<<<(3072 * 128) / 256, 256, 0, stream>>>(w_ih1, wz1_b);
  build_wext15_kernel<<<(3072 * 32) / 256, 256, 0, stream>>>(w_ih1, w15_b);
  build_aext15_kernel<<<(T_SZ * B_SZ * 32) / 256, 256, 0, stream>>>(rhy, cond, a15);
  build_wih1T_kernel<<<(NROLL * 3072 + 255) / 256, 256, 0, stream>>>(w_ih1, wih1T);
  bext_kernel<<<dim3(B_SZ / 128, 3072 / 64), 256, 0, stream>>>(z1b, wz1_b, bext);
  init_h1_mfma_kernel<<<dim3(B_SZ / 128, H_SZ / 64), 256, 0, stream>>>(z1b, winitb, b_init, h1f, h1b[0]);
  init_amax_kernel<<<B_SZ / 256, 256, 0, stream>>>(amax);

  // passthrough outputs 1..5
  size_t o_rhy = (size_t)B_SZ * T_SZ * NROLL;
  size_t o_d1m = o_rhy + (size_t)B_SZ * T_SZ * 3;
  size_t o_d1s = o_d1m + (size_t)B_SZ * 128;
  size_t o_d2m = o_d1s + (size_t)B_SZ * 128;
  size_t o_d2s = o_d2m + (size_t)B_SZ * 128;
  hipMemcpyAsync(out + o_rhy, rhy, (size_t)B_SZ * T_SZ * 3 * 4, hipMemcpyDeviceToDevice, stream);
  hipMemcpyAsync(out + o_d1m, d1m, (size_t)B_SZ * 128 * 4, hipMemcpyDeviceToDevice, stream);
  hipMemcpyAsync(out + o_d1s, d1s, (size_t)B_SZ * 128 * 4, hipMemcpyDeviceToDevice, stream);
  hipMemcpyAsync(out + o_d2m, d2m, (size_t)B_SZ * 128 * 4, hipMemcpyDeviceToDevice, stream);
  hipMemcpyAsync(out + o_d2s, d2s, (size_t)B_SZ * 128 * 4, hipMemcpyDeviceToDevice, stream);

  dim3 ggrid(B_SZ / 128, H_SZ / 64);
  for (int t = 0; t < T_SZ; ++t) {
    const u16* h1in = h1b[t & 1];
    u16* h1out = h1b[(t & 1) ^ 1];
    gru1_kernel<<<ggrid, 256, 0, stream>>>(h1in, whh1_b, a15 + (size_t)t * B_SZ * 32,
                                           w15_b, bext, wih1T, b_ih1, b_hh1, amax, h1f, h1out);
    const u16* h2in = (t == 0) ? (const u16*)h1out : h2b[t & 1];
    const float* hpf = (t == 0) ? h1f : h2f;
    u16* h2out = h2b[(t & 1) ^ 1];
    gru2_kernel<<<ggrid, 256, 0, stream>>>(h1out, h2in, wih2_b, whh2_b, b_ih2, b_hh2,
                                           hpf, h2f, h2out);
    out_kernel<<<B_SZ / 16, 128, 0, stream>>>(h2out, wout_b, b_out, out, amax, t);
  }
  (void)in_sizes; (void)n_in; (void)out_size; (void)ws_size;
}

// Round 15
// 3575.320 us; speedup vs baseline: 1.0977x; 1.0158x over previous
//
#include <hip/hip_runtime.h>
#include <stdint.h>

typedef unsigned short u16;
typedef unsigned int u32;
typedef __attribute__((ext_vector_type(4))) float f32x4;
typedef __attribute__((ext_vector_type(8))) short short8;

#define MFMA16(a, b, c) __builtin_amdgcn_mfma_f32_16x16x32_bf16(a, b, c, 0, 0, 0)

// ---------- sizes ----------
#define B_SZ   4096
#define H_SZ   1024
#define T_SZ   32
#define NROLL  130
#define NCPAD  144   // 130 padded to 9x16

__device__ __forceinline__ u16 f2b(float f) {
  u32 u = __float_as_uint(f);
  u += 0x7FFFu + ((u >> 16) & 1u);
  return (u16)(u >> 16);
}
__device__ __forceinline__ float b2f(u16 b) {
  return __uint_as_float(((u32)b) << 16);
}
__device__ __forceinline__ float sigm(float x) { return 1.f / (1.f + __expf(-x)); }

// async global->LDS (16B). LDS dest = wave-uniform base + lane*16 (linear).
__device__ __forceinline__ void gld16(const void* g, const void* lds) {
  __builtin_amdgcn_global_load_lds(
      (const __attribute__((address_space(1))) u32*)(uintptr_t)g,
      (__attribute__((address_space(3))) u32*)(u32)(uintptr_t)lds, 16, 0, 0);
}

// ---------------- setup kernels ----------------
__global__ void cvt_kernel(const float* __restrict__ s, u16* __restrict__ d, int n) {
  int i = blockIdx.x * 256 + threadIdx.x;
  if (i < n) d[i] = f2b(s[i]);
}

__global__ void build_wout_kernel(const float* __restrict__ w, u16* __restrict__ d) {
  int i = blockIdx.x * 256 + threadIdx.x;           // 144*1024
  int r = i >> 10, c = i & 1023;
  d[i] = f2b(r < NROLL ? w[r * H_SZ + c] : 0.f);
}

// Wz1[j][k] = w_ih1[j][133+k], j in 0..3071, k in 0..127 (z1 slice, all 3 gates)
__global__ void build_wz1_kernel(const float* __restrict__ w, u16* __restrict__ d) {
  int i = blockIdx.x * 256 + threadIdx.x;           // 3072*128
  int j = i >> 7, k = i & 127;
  d[i] = f2b(w[j * 273 + 133 + k]);
}

// W15[j][k]: k<3 -> rhy cols (130+k); k<15 -> cond cols (261+k-3); else 0. [3072][32]
__global__ void build_wext15_kernel(const float* __restrict__ w, u16* __restrict__ d) {
  int i = blockIdx.x * 256 + threadIdx.x;           // 3072*32
  int j = i >> 5, k = i & 31;
  float v = 0.f;
  if (k < 3)       v = w[j * 273 + 130 + k];
  else if (k < 15) v = w[j * 273 + 261 + (k - 3)];
  d[i] = f2b(v);
}

// A15[t][b][k]: k<3 -> rhy[b][t][k]; k<15 -> cond[b][t][k-3]; else 0. [32][4096][32]
__global__ void build_aext15_kernel(const float* __restrict__ rhy, const float* __restrict__ cond,
                                    u16* __restrict__ d) {
  int i = blockIdx.x * 256 + threadIdx.x;           // 32*4096*32 = 4194304
  int k = i & 31;
  int b = (i >> 5) & 4095;
  int t = i >> 17;
  float v = 0.f;
  if (k < 3)       v = rhy[b * (T_SZ * 3) + t * 3 + k];
  else if (k < 15) v = cond[b * (T_SZ * 12) + t * 12 + (k - 3)];
  d[i] = f2b(v);
}

// wih1T[c][j] = w_ih1[j][c] for c < 130 (one-hot gather rows, bf16)
__global__ void build_wih1T_kernel(const float* __restrict__ w, u16* __restrict__ d) {
  int i = blockIdx.x * 256 + threadIdx.x;           // 130*3072
  if (i >= NROLL * 3072) return;
  int c = i / 3072, j = i % 3072;
  d[i] = f2b(w[j * 273 + c]);
}

__global__ void init_amax_kernel(int* __restrict__ a) {
  a[blockIdx.x * 256 + threadIdx.x] = NROLL - 1;  // one-hot at last col
}

// bext[b][j] = sum_k z1[b][k] * Wz1[j][k]  (bf16 out, no bias). 128x64 tile, K=128.
__global__ __launch_bounds__(256, 2)
void bext_kernel(const u16* __restrict__ Az,   // z1 bf16 [4096][128]
                 const u16* __restrict__ Wz,   // Wz1 bf16 [3072][128]
                 u16* __restrict__ bext) {
  __shared__ u16 As[128 * 64];
  __shared__ u16 Ws[64 * 64];
  const int tid = threadIdx.x;
  const int lane = tid & 63, wv = tid >> 6;
  const int wm = wv >> 1, wn = wv & 1;
  const int lr = lane & 15, lk = lane >> 4;
  const int Mbase = blockIdx.x * 128, Nbase = blockIdx.y * 64;

  f32x4 zero = {0.f, 0.f, 0.f, 0.f};
  f32x4 acc[4][2];
#pragma unroll
  for (int m = 0; m < 4; ++m)
#pragma unroll
    for (int n = 0; n < 2; ++n) acc[m][n] = zero;

  for (int it = 0; it < 2; ++it) {
#pragma unroll
    for (int i = 0; i < 4; ++i) {
      int seg = i * 256 + tid, row = seg >> 3, c8 = seg & 7;
      gld16(Az + (size_t)(Mbase + row) * 128 + it * 64 + c8 * 8, As + ((i * 256 + (wv << 6)) << 3));
    }
#pragma unroll
    for (int i = 0; i < 2; ++i) {
      int seg = i * 256 + tid, row = seg >> 3, c8 = seg & 7;
      gld16(Wz + (size_t)(Nbase + row) * 128 + it * 64 + c8 * 8, Ws + ((i * 256 + (wv << 6)) << 3));
    }
    __syncthreads();
#pragma unroll
    for (int kk = 0; kk < 2; ++kk) {
      short8 af[4];
#pragma unroll
      for (int m = 0; m < 4; ++m)
        af[m] = *(const short8*)(As + (((wm << 6) + (m << 4) + lr) << 6) + kk * 32 + (lk << 3));
      short8 bw[2];
#pragma unroll
      for (int n = 0; n < 2; ++n)
        bw[n] = *(const short8*)(Ws + ((((wn << 5) + (n << 4) + lr)) << 6) + kk * 32 + (lk << 3));
#pragma unroll
      for (int m = 0; m < 4; ++m)
#pragma unroll
        for (int n = 0; n < 2; ++n)
          acc[m][n] = MFMA16(af[m], bw[n], acc[m][n]);
    }
    __syncthreads();
  }

  int jcol[2];
  jcol[0] = Nbase + (wn << 5) + lr;
  jcol[1] = jcol[0] + 16;
#pragma unroll
  for (int m = 0; m < 4; ++m) {
#pragma unroll
    for (int q = 0; q < 4; ++q) {
      int b = Mbase + (wm << 6) + (m << 4) + (lk << 2) + q;
#pragma unroll
      for (int n = 0; n < 2; ++n)
        bext[(size_t)b * 3072 + jcol[n]] = f2b(acc[m][n][q]);
    }
  }
}

// h1_0 = tanh(z1 @ w_init^T + b_init), MFMA.
__global__ __launch_bounds__(256, 2)
void init_h1_mfma_kernel(const u16* __restrict__ Az,  // z1 bf16 [4096][128]
                         const u16* __restrict__ Wz,  // w_init bf16 [1024][128]
                         const float* __restrict__ b_init,
                         float* __restrict__ h1f, u16* __restrict__ h1b) {
  __shared__ u16 As[128 * 64];
  __shared__ u16 Ws[64 * 64];
  const int tid = threadIdx.x;
  const int lane = tid & 63, wv = tid >> 6;
  const int wm = wv >> 1, wn = wv & 1;
  const int lr = lane & 15, lk = lane >> 4;
  const int Mbase = blockIdx.x * 128, Nbase = blockIdx.y * 64;

  f32x4 zero = {0.f, 0.f, 0.f, 0.f};
  f32x4 acc[4][2];
#pragma unroll
  for (int m = 0; m < 4; ++m)
#pragma unroll
    for (int n = 0; n < 2; ++n) acc[m][n] = zero;

  for (int it = 0; it < 2; ++it) {
#pragma unroll
    for (int i = 0; i < 4; ++i) {
      int seg = i * 256 + tid, row = seg >> 3, c8 = seg & 7;
      gld16(Az + (size_t)(Mbase + row) * 128 + it * 64 + c8 * 8, As + ((i * 256 + (wv << 6)) << 3));
    }
#pragma unroll
    for (int i = 0; i < 2; ++i) {
      int seg = i * 256 + tid, row = seg >> 3, c8 = seg & 7;
      gld16(Wz + (size_t)(Nbase + row) * 128 + it * 64 + c8 * 8, Ws + ((i * 256 + (wv << 6)) << 3));
    }
    __syncthreads();
#pragma unroll
    for (int kk = 0; kk < 2; ++kk) {
      short8 af[4];
#pragma unroll
      for (int m = 0; m < 4; ++m)
        af[m] = *(const short8*)(As + (((wm << 6) + (m << 4) + lr) << 6) + kk * 32 + (lk << 3));
      short8 bw[2];
#pragma unroll
      for (int n = 0; n < 2; ++n)
        bw[n] = *(const short8*)(Ws + ((((wn << 5) + (n << 4) + lr)) << 6) + kk * 32 + (lk << 3));
#pragma unroll
      for (int m = 0; m < 4; ++m)
#pragma unroll
        for (int n = 0; n < 2; ++n)
          acc[m][n] = MFMA16(af[m], bw[n], acc[m][n]);
    }
    __syncthreads();
  }

  int hcol[2];
  hcol[0] = Nbase + (wn << 5) + lr;
  hcol[1] = hcol[0] + 16;
#pragma unroll
  for (int m = 0; m < 4; ++m) {
#pragma unroll
    for (int q = 0; q < 4; ++q) {
      int b = Mbase + (wm << 6) + (m << 4) + (lk << 2) + q;
      size_t ho = (size_t)b << 10;
#pragma unroll
      for (int n = 0; n < 2; ++n) {
        int h = hcol[n];
        float v = tanhf(acc[m][n][q] + b_init[h]);
        h1f[ho + h] = v;
        h1b[ho + h] = f2b(v);
      }
    }
  }
}

// ---- GRU cell 1: 8x BK=128 main + 1x BK=32 rhy/cond mini-iter + bf16 table epilogue ----
__global__ __launch_bounds__(256, 2)
void gru1_kernel(const u16* __restrict__ Ah,   // h1 bf16 [B][1024]
                 const u16* __restrict__ Whh,  // w_hh1 bf16 [3072][1024]
                 const u16* __restrict__ A15,  // rhy/cond bf16 [B][32] (this t)
                 const u16* __restrict__ W15,  // bf16 [3072][32]
                 const u16* __restrict__ bext, // z1-part gi [B][3072] bf16
                 const u16* __restrict__ gT,   // w_ih1T [130][3072] bf16
                 const float* __restrict__ bih, const float* __restrict__ bhh,
                 const int* __restrict__ amax,
                 float* __restrict__ h1f, u16* __restrict__ h1o) {
  __shared__ u16 smem[40960];   // 80 KB: As 128x128 (32KB) + Ws 192x128 (48KB)
  u16* As = smem;
  u16* Wsm = smem + 16384;
  const int tid = threadIdx.x;
  const int lane = tid & 63, wv = tid >> 6;
  const int wm = wv >> 1, wn = wv & 1;
  const int lr = lane & 15, lk = lane >> 4;
  const int Mbase = blockIdx.x * 128, Nbase = blockIdx.y * 64;

  f32x4 zero = {0.f, 0.f, 0.f, 0.f};
  f32x4 acc_r[4][2], acc_z[4][2], acc_hn[4][2], acc_in[4][2];
#pragma unroll
  for (int m = 0; m < 4; ++m)
#pragma unroll
    for (int n = 0; n < 2; ++n) { acc_r[m][n] = zero; acc_z[m][n] = zero; acc_hn[m][n] = zero; acc_in[m][n] = zero; }

  // ---- main phase: K=1024 in 8 iters of BK=128 ----
#pragma unroll 1
  for (int it = 0; it < 8; ++it) {
#pragma unroll
    for (int i = 0; i < 8; ++i) {     // A: 128 rows x 128 cols
      int seg = i * 256 + tid, row = seg >> 4, c16 = (seg & 15) ^ (row & 7);
      gld16(Ah + (size_t)(Mbase + row) * 1024 + it * 128 + c16 * 8, As + ((i * 256 + (wv << 6)) << 3));
    }
#pragma unroll
    for (int i = 0; i < 12; ++i) {    // W: 192 rows x 128 cols
      int seg = i * 256 + tid, gr = seg >> 4, c16 = (seg & 15) ^ (gr & 7);
      int gg = gr >> 6, r = gr & 63;
      gld16(Whh + ((size_t)(gg << 10) + Nbase + r) * 1024 + it * 128 + c16 * 8,
            Wsm + ((i * 256 + (wv << 6)) << 3));
    }
    __syncthreads();
    __builtin_amdgcn_s_setprio(1);
#pragma unroll
    for (int kk = 0; kk < 4; ++kk) {
      int gc = (kk << 2) + lk;        // global chunk16 wanted
      short8 af[4];
#pragma unroll
      for (int m = 0; m < 4; ++m) {
        int row = (wm << 6) + (m << 4) + lr;
        af[m] = *(const short8*)(As + (row << 7) + ((gc ^ (row & 7)) << 3));
      }
      short8 bw[3][2];
#pragma unroll
      for (int g = 0; g < 3; ++g)
#pragma unroll
        for (int n = 0; n < 2; ++n) {
          int row = (g << 6) + (wn << 5) + (n << 4) + lr;
          bw[g][n] = *(const short8*)(Wsm + (row << 7) + ((gc ^ (row & 7)) << 3));
        }
#pragma unroll
      for (int m = 0; m < 4; ++m)
#pragma unroll
        for (int n = 0; n < 2; ++n) {
          acc_r[m][n] = MFMA16(af[m], bw[0][n], acc_r[m][n]);
          acc_z[m][n] = MFMA16(af[m], bw[1][n], acc_z[m][n]);
          acc_hn[m][n] = MFMA16(af[m], bw[2][n], acc_hn[m][n]);
        }
    }
    __builtin_amdgcn_s_setprio(0);
    __syncthreads();
  }

  // ---- mini ext iter: K=32 (rhy 3 + cond 12, zero-padded) ----
  {
#pragma unroll
    for (int i = 0; i < 2; ++i) {     // A15: 128 rows x 4 chunks
      int seg = i * 256 + tid, row = seg >> 2, c4 = (seg & 3) ^ (row & 3);
      gld16(A15 + (size_t)(Mbase + row) * 32 + c4 * 8, As + ((i * 256 + (wv << 6)) << 3));
    }
#pragma unroll
    for (int i = 0; i < 3; ++i) {     // W15: 192 rows x 4 chunks
      int seg = i * 256 + tid, gr = seg >> 2, c4 = (seg & 3) ^ (gr & 3);
      int gg = gr >> 6, r = gr & 63;
      gld16(W15 + ((size_t)(gg << 10) + Nbase + r) * 32 + c4 * 8,
            Wsm + ((i * 256 + (wv << 6)) << 3));
    }
    __syncthreads();
    __builtin_amdgcn_s_setprio(1);
    short8 af[4];
#pragma unroll
    for (int m = 0; m < 4; ++m) {
      int row = (wm << 6) + (m << 4) + lr;
      af[m] = *(const short8*)(As + (row << 5) + (((lk) ^ (row & 3)) << 3));
    }
    short8 bw[3][2];
#pragma unroll
    for (int g = 0; g < 3; ++g)
#pragma unroll
      for (int n = 0; n < 2; ++n) {
        int row = (g << 6) + (wn << 5) + (n << 4) + lr;
        bw[g][n] = *(const short8*)(Wsm + (row << 5) + (((lk) ^ (row & 3)) << 3));
      }
#pragma unroll
    for (int m = 0; m < 4; ++m)
#pragma unroll
      for (int n = 0; n < 2; ++n) {
        acc_r[m][n] = MFMA16(af[m], bw[0][n], acc_r[m][n]);
        acc_z[m][n] = MFMA16(af[m], bw[1][n], acc_z[m][n]);
        acc_in[m][n] = MFMA16(af[m], bw[2][n], acc_in[m][n]);
      }
    __builtin_amdgcn_s_setprio(0);
    __syncthreads();
  }

  // epilogue: + bias + bext(z1 part, bf16) + one-hot gather (bf16), GRU nonlinearity
  int hcol[2];
  hcol[0] = Nbase + (wn << 5) + lr;
  hcol[1] = hcol[0] + 16;
  float bi0[2], bi1[2], bi2[2], bh0[2], bh1[2], bh2[2];
#pragma unroll
  for (int n = 0; n < 2; ++n) {
    int h = hcol[n];
    bi0[n] = bih[h]; bi1[n] = bih[1024 + h]; bi2[n] = bih[2048 + h];
    bh0[n] = bhh[h]; bh1[n] = bhh[1024 + h]; bh2[n] = bhh[2048 + h];
  }
#pragma unroll
  for (int m = 0; m < 4; ++m) {
#pragma unroll
    for (int q = 0; q < 4; ++q) {
      int b = Mbase + (wm << 6) + (m << 4) + (lk << 2) + q;
      const u16* gRow = gT + (size_t)amax[b] * 3072;
      const u16* bx = bext + (size_t)b * 3072;
      size_t ho = (size_t)b << 10;
#pragma unroll
      for (int n = 0; n < 2; ++n) {
        int h = hcol[n];
        float rp = acc_r[m][n][q] + bi0[n] + bh0[n] + b2f(gRow[h]) + b2f(bx[h]);
        float zp = acc_z[m][n][q] + bi1[n] + bh1[n] + b2f(gRow[1024 + h]) + b2f(bx[1024 + h]);
        float inp = acc_in[m][n][q] + bi2[n] + b2f(gRow[2048 + h]) + b2f(bx[2048 + h]);
        float hnp = acc_hn[m][n][q] + bh2[n];
        float r = sigm(rp), z = sigm(zp);
        float nn = tanhf(inp + r * hnp);
        float hv = (1.f - z) * nn + z * h1f[ho + h];
        h1f[ho + h] = hv;
        h1o[ho + h] = f2b(hv);
      }
    }
  }
}

// ---- GRU cell 2 (fused gi2+gh2): lockstep BK=64, XOR chunk swizzle, T5 setprio (R9) ----
__global__ __launch_bounds__(256, 2)
void gru2_kernel(const u16* __restrict__ A1,  // h1_new bf16
                 const u16* __restrict__ A2,  // h2_prev bf16 (h1_new at t=0)
                 const u16* __restrict__ Wi,  // w_ih2 bf16
                 const u16* __restrict__ Wh,  // w_hh2 bf16
                 const float* __restrict__ bih, const float* __restrict__ bhh,
                 const float* __restrict__ hpf,  // h2_prev f32 (h1f at t=0)
                 float* __restrict__ h2f, u16* __restrict__ h2o) {
  __shared__ u16 As1[128 * 64];
  __shared__ u16 As2[128 * 64];
  __shared__ u16 Ws[384 * 64];
  const int tid = threadIdx.x;
  const int lane = tid & 63, wv = tid >> 6;
  const int wm = wv >> 1, wn = wv & 1;
  const int lr = lane & 15, lk = lane >> 4;
  const int Mbase = blockIdx.x * 128, Nbase = blockIdx.y * 64;

  f32x4 zero = {0.f, 0.f, 0.f, 0.f};
  f32x4 acc_r[4][2], acc_z[4][2], acc_hn[4][2], acc_in[4][2];
#pragma unroll
  for (int m = 0; m < 4; ++m)
#pragma unroll
    for (int n = 0; n < 2; ++n) { acc_r[m][n] = zero; acc_z[m][n] = zero; acc_hn[m][n] = zero; acc_in[m][n] = zero; }

#pragma unroll 1
  for (int it = 0; it < 16; ++it) {
#pragma unroll
    for (int i = 0; i < 4; ++i) {
      int seg = i * 256 + tid, row = seg >> 3, c8 = (seg & 7) ^ (row & 7);
      size_t go = (size_t)(Mbase + row) * 1024 + it * 64 + c8 * 8;
      gld16(A1 + go, As1 + ((i * 256 + (wv << 6)) << 3));
      gld16(A2 + go, As2 + ((i * 256 + (wv << 6)) << 3));
    }
#pragma unroll
    for (int i = 0; i < 12; ++i) {
      int seg = i * 256 + tid, gr = seg >> 3, c8 = (seg & 7) ^ (gr & 7);
      int s = gr >> 6, r = gr & 63;
      const u16* Wm = (s < 3) ? Wi : Wh;
      int gate = (s < 3) ? s : (s - 3);
      gld16(Wm + ((size_t)(gate << 10) + Nbase + r) * 1024 + it * 64 + c8 * 8,
            Ws + ((i * 256 + (wv << 6)) << 3));
    }
    __syncthreads();
    __builtin_amdgcn_s_setprio(1);
#pragma unroll
    for (int kk = 0; kk < 2; ++kk) {
      int gc = (kk << 2) + lk;
      short8 a1[4], a2[4];
#pragma unroll
      for (int m = 0; m < 4; ++m) {
        int row = (wm << 6) + (m << 4) + lr;
        int off = (row << 6) + ((gc ^ (row & 7)) << 3);
        a1[m] = *(const short8*)(As1 + off);
        a2[m] = *(const short8*)(As2 + off);
      }
      short8 bw[6][2];
#pragma unroll
      for (int s = 0; s < 6; ++s)
#pragma unroll
        for (int n = 0; n < 2; ++n) {
          int row = (s << 6) + (wn << 5) + (n << 4) + lr;
          bw[s][n] = *(const short8*)(Ws + (row << 6) + ((gc ^ (row & 7)) << 3));
        }
#pragma unroll
      for (int m = 0; m < 4; ++m)
#pragma unroll
        for (int n = 0; n < 2; ++n) {
          acc_r[m][n] = MFMA16(a1[m], bw[0][n], acc_r[m][n]);
          acc_r[m][n] = MFMA16(a2[m], bw[3][n], acc_r[m][n]);
          acc_z[m][n] = MFMA16(a1[m], bw[1][n], acc_z[m][n]);
          acc_z[m][n] = MFMA16(a2[m], bw[4][n], acc_z[m][n]);
          acc_in[m][n] = MFMA16(a1[m], bw[2][n], acc_in[m][n]);
          acc_hn[m][n] = MFMA16(a2[m], bw[5][n], acc_hn[m][n]);
        }
    }
    __builtin_amdgcn_s_setprio(0);
    __syncthreads();
  }

  int hcol[2];
  hcol[0] = Nbase + (wn << 5) + lr;
  hcol[1] = hcol[0] + 16;
  float bi0[2], bi1[2], bi2[2], bh0[2], bh1[2], bh2[2];
#pragma unroll
  for (int n = 0; n < 2; ++n) {
    int h = hcol[n];
    bi0[n] = bih[h]; bi1[n] = bih[1024 + h]; bi2[n] = bih[2048 + h];
    bh0[n] = bhh[h]; bh1[n] = bhh[1024 + h]; bh2[n] = bhh[2048 + h];
  }
#pragma unroll
  for (int m = 0; m < 4; ++m) {
#pragma unroll
    for (int q = 0; q < 4; ++q) {
      int b = Mbase + (wm << 6) + (m << 4) + (lk << 2) + q;
      size_t ho = (size_t)b << 10;
#pragma unroll
      for (int n = 0; n < 2; ++n) {
        int h = hcol[n];
        float r = sigm(acc_r[m][n][q] + bi0[n] + bh0[n]);
        float z = sigm(acc_z[m][n][q] + bi1[n] + bh1[n]);
        float nn = tanhf(acc_in[m][n][q] + bi2[n] + r * (acc_hn[m][n][q] + bh2[n]));
        float hv = (1.f - z) * nn + z * hpf[ho + h];
        h2f[ho + h] = hv;
        h2o[ho + h] = f2b(hv);
      }
    }
  }
}

// ---- logits + log_softmax + argmax: 256 blocks x 128 threads, BK=128 (8 drains) ----
__global__ __launch_bounds__(128)
void out_kernel(const u16* __restrict__ A,   // h2_new bf16
                const u16* __restrict__ W,   // wout bf16 [144][1024]
                const float* __restrict__ b_out,
                float* __restrict__ recon, int* __restrict__ amax_out, int t) {
  __shared__ u16 As[16 * 128];   // 4 KB
  __shared__ u16 Ws[144 * 128];  // 36 KB
  __shared__ float redm[2][16], reds[2][16], logZs[16];
  __shared__ int redi[2][16];
  const int tid = threadIdx.x;
  const int lane = tid & 63, wv = tid >> 6;   // 2 waves
  const int lr = lane & 15, lk = lane >> 4;
  const int bb = blockIdx.x;  // 16 rows each
  const int nf0 = wv ? 5 : 0;                 // first owned frag
  const int nfn = wv ? 4 : 5;                 // owned frag count

  f32x4 zero = {0.f, 0.f, 0.f, 0.f};
  f32x4 acc[5];
#pragma unroll
  for (int j = 0; j < 5; ++j) acc[j] = zero;

  float bo[5];
#pragma unroll
  for (int j = 0; j < 5; ++j) {
    int col = ((nf0 + j) << 4) + lr;
    bo[j] = (j < nfn && col < NROLL) ? b_out[col] : -1e30f;
  }

#pragma unroll 1
  for (int it = 0; it < 8; ++it) {
#pragma unroll
    for (int i = 0; i < 2; ++i) {  // A: 16 x 128
      int seg = i * 128 + tid, row = seg >> 4, c16 = seg & 15;
      gld16(A + (size_t)(bb * 16 + row) * 1024 + it * 128 + c16 * 8, As + ((i * 128 + (wv << 6)) << 3));
    }
#pragma unroll
    for (int i = 0; i < 18; ++i) { // W: 144 x 128
      int seg = i * 128 + tid, row = seg >> 4, c16 = seg & 15;
      gld16(W + (size_t)row * 1024 + it * 128 + c16 * 8, Ws + ((i * 128 + (wv << 6)) << 3));
    }
    __syncthreads();
#pragma unroll
    for (int kk = 0; kk < 4; ++kk) {
      short8 af = *(const short8*)(As + (lr << 7) + kk * 32 + (lk << 3));
#pragma unroll 5
      for (int j = 0; j < 5; ++j) {
        if (j < nfn) {
          short8 bw = *(const short8*)(Ws + ((((nf0 + j) << 4) + lr) << 7) + kk * 32 + (lk << 3));
          acc[j] = MFMA16(af, bw, acc[j]);
        }
      }
    }
    __syncthreads();
  }

#pragma unroll
  for (int q = 0; q < 4; ++q) {
    int r = (lk << 2) + q;
    float vmax = -1e30f; int vidx = 0;
#pragma unroll 5
    for (int j = 0; j < 5; ++j) {
      if (j < nfn) {
        int col = ((nf0 + j) << 4) + lr;
        float x = acc[j][q] + bo[j];
        if (x > vmax) { vmax = x; vidx = col; }
      }
    }
    for (int d = 1; d < 16; d <<= 1) {
      float om = __shfl_xor(vmax, d);
      int oi = __shfl_xor(vidx, d);
      if (om > vmax || (om == vmax && oi < vidx)) { vmax = om; vidx = oi; }
    }
    float s = 0.f;
#pragma unroll 5
    for (int j = 0; j < 5; ++j) {
      if (j < nfn) s += __expf(acc[j][q] + bo[j] - vmax);
    }
    for (int d = 1; d < 16; d <<= 1) s += __shfl_xor(s, d);
    if (lr == 0) { redm[wv][r] = vmax; reds[wv][r] = s; redi[wv][r] = vidx; }
  }
  __syncthreads();

  if (tid < 16) {
    float m0 = redm[0][tid], m1 = redm[1][tid];
    float s0 = reds[0][tid], s1 = reds[1][tid];
    float M = fmaxf(m0, m1);
    float S = s0 * __expf(m0 - M) + s1 * __expf(m1 - M);
    logZs[tid] = M + __logf(S);
    amax_out[bb * 16 + tid] = (m1 > m0) ? redi[1][tid] : redi[0][tid];
  }
  __syncthreads();

#pragma unroll
  for (int q = 0; q < 4; ++q) {
    int r = (lk << 2) + q;
    int b = bb * 16 + r;
    float lz = logZs[r];
#pragma unroll 5
    for (int j = 0; j < 5; ++j) {
      if (j < nfn) {
        int col = ((nf0 + j) << 4) + lr;
        if (col < NROLL)
          recon[(size_t)b * (T_SZ * NROLL) + t * NROLL + col] = acc[j][q] + bo[j] - lz;
      }
    }
  }
}

// ---------------- host ----------------
extern "C" void kernel_launch(void* const* d_in, const int* in_sizes, int n_in,
                              void* d_out, int out_size, void* d_ws, size_t ws_size,
                              hipStream_t stream) {
  const float* z1    = (const float*)d_in[0];
  const float* d1m   = (const float*)d_in[1];
  const float* d1s   = (const float*)d_in[2];
  const float* d2m   = (const float*)d_in[3];
  const float* d2s   = (const float*)d_in[4];
  const float* rhy   = (const float*)d_in[5];
  const float* cond  = (const float*)d_in[7];
  const float* w_ih1 = (const float*)d_in[9];
  const float* w_hh1 = (const float*)d_in[10];
  const float* b_ih1 = (const float*)d_in[11];
  const float* b_hh1 = (const float*)d_in[12];
  const float* w_ih2 = (const float*)d_in[13];
  const float* w_hh2 = (const float*)d_in[14];
  const float* b_ih2 = (const float*)d_in[15];
  const float* b_hh2 = (const float*)d_in[16];
  const float* w_init = (const float*)d_in[17];
  const float* b_init = (const float*)d_in[18];
  const float* w_out  = (const float*)d_in[19];
  const float* b_out  = (const float*)d_in[20];
  float* out = (float*)d_out;

  char* ws = (char*)d_ws;
  size_t off = 0;
  auto alloc = [&](size_t bytes) -> void* {
    off = (off + 255) & ~(size_t)255;
    void* p = ws + off;
    off += bytes;
    return p;
  };
  u16* whh1_b = (u16*)alloc((size_t)3072 * 1024 * 2);
  u16* wih2_b = (u16*)alloc((size_t)3072 * 1024 * 2);
  u16* whh2_b = (u16*)alloc((size_t)3072 * 1024 * 2);
  u16* wout_b = (u16*)alloc((size_t)NCPAD * 1024 * 2);
  u16* wz1_b  = (u16*)alloc((size_t)3072 * 128 * 2);
  u16* w15_b  = (u16*)alloc((size_t)3072 * 32 * 2);
  u16* a15    = (u16*)alloc((size_t)T_SZ * B_SZ * 32 * 2);
  u16* bext   = (u16*)alloc((size_t)B_SZ * 3072 * 2);
  u16* wih1T  = (u16*)alloc((size_t)NROLL * 3072 * 2);
  float* h1f  = (float*)alloc((size_t)B_SZ * H_SZ * 4);
  float* h2f  = (float*)alloc((size_t)B_SZ * H_SZ * 4);
  u16* h1b[2];
  h1b[0] = (u16*)alloc((size_t)B_SZ * H_SZ * 2);
  h1b[1] = (u16*)alloc((size_t)B_SZ * H_SZ * 2);
  u16* h2b[2];
  h2b[0] = (u16*)alloc((size_t)B_SZ * H_SZ * 2);
  h2b[1] = (u16*)alloc((size_t)B_SZ * H_SZ * 2);
  int* amax = (int*)alloc((size_t)B_SZ * 4);
  u16* z1b    = (u16*)alloc((size_t)B_SZ * 128 * 2);
  u16* winitb = (u16*)alloc((size_t)H_SZ * 128 * 2);

  const int NW = 3072 * 1024;
  cvt_kernel<<<(NW + 255) / 256, 256, 0, stream>>>(w_hh1, whh1_b, NW);
  cvt_kernel<<<(NW + 255) / 256, 256, 0, stream>>>(w_ih2, wih2_b, NW);
  cvt_kernel<<<(NW + 255) / 256, 256, 0, stream>>>(w_hh2, whh2_b, NW);
  cvt_kernel<<<(B_SZ * 128 + 255) / 256, 256, 0, stream>>>(z1, z1b, B_SZ * 128);
  cvt_kernel<<<(H_SZ * 128 + 255) / 256, 256, 0, stream>>>(w_init, winitb, H_SZ * 128);
  build_wout_kernel<<<(NCPAD * 1024) / 256, 256, 0, stream>>>(w_out, wout_b);
  build_wz1_kernel<<<(3072 * 128) / 256, 256, 0, stream>>>(w_ih1, wz1_b);
  build_wext15_kernel<<<(3072 * 32) / 256, 256, 0, stream>>>(w_ih1, w15_b);
  build_aext15_kernel<<<(T_SZ * B_SZ * 32) / 256, 256, 0, stream>>>(rhy, cond, a15);
  build_wih1T_kernel<<<(NROLL * 3072 + 255) / 256, 256, 0, stream>>>(w_ih1, wih1T);
  bext_kernel<<<dim3(B_SZ / 128, 3072 / 64), 256, 0, stream>>>(z1b, wz1_b, bext);
  init_h1_mfma_kernel<<<dim3(B_SZ / 128, H_SZ / 64), 256, 0, stream>>>(z1b, winitb, b_init, h1f, h1b[0]);
  init_amax_kernel<<<B_SZ / 256, 256, 0, stream>>>(amax);

  // passthrough outputs 1..5
  size_t o_rhy = (size_t)B_SZ * T_SZ * NROLL;
  size_t o_d1m = o_rhy + (size_t)B_SZ * T_SZ * 3;
  size_t o_d1s = o_d1m + (size_t)B_SZ * 128;
  size_t o_d2m = o_d1s + (size_t)B_SZ * 128;
  size_t o_d2s = o_d2m + (size_t)B_SZ * 128;
  hipMemcpyAsync(out + o_rhy, rhy, (size_t)B_SZ * T_SZ * 3 * 4, hipMemcpyDeviceToDevice, stream);
  hipMemcpyAsync(out + o_d1m, d1m, (size_t)B_SZ * 128 * 4, hipMemcpyDeviceToDevice, stream);
  hipMemcpyAsync(out + o_d1s, d1s, (size_t)B_SZ * 128 * 4, hipMemcpyDeviceToDevice, stream);
  hipMemcpyAsync(out + o_d2m, d2m, (size_t)B_SZ * 128 * 4, hipMemcpyDeviceToDevice, stream);
  hipMemcpyAsync(out + o_d2s, d2s, (size_t)B_SZ * 128 * 4, hipMemcpyDeviceToDevice, stream);

  dim3 ggrid(B_SZ / 128, H_SZ / 64);
  for (int t = 0; t < T_SZ; ++t) {
    const u16* h1in = h1b[t & 1];
    u16* h1out = h1b[(t & 1) ^ 1];
    gru1_kernel<<<ggrid, 256, 0, stream>>>(h1in, whh1_b, a15 + (size_t)t * B_SZ * 32,
                                           w15_b, bext, wih1T, b_ih1, b_hh1, amax, h1f, h1out);
    const u16* h2in = (t == 0) ? (const u16*)h1out : h2b[t & 1];
    const float* hpf = (t == 0) ? h1f : h2f;
    u16* h2out = h2b[(t & 1) ^ 1];
    gru2_kernel<<<ggrid, 256, 0, stream>>>(h1out, h2in, wih2_b, whh2_b, b_ih2, b_hh2,
                                           hpf, h2f, h2out);
    out_kernel<<<B_SZ / 16, 128, 0, stream>>>(h2out, wout_b, b_out, out, amax, t);
  }
  (void)in_sizes; (void)n_in; (void)out_size; (void)ws_size;
}